// Round 4
// baseline (564.936 us; speedup 1.0000x reference)
//
#include <hip/hip_runtime.h>
#include <hip/hip_fp16.h>
#include <cstdint>
#include <cstddef>

// ---------------------------------------------------------------------------
// GCN: 3x GraphConv(norm='both') + linear head, fp32 in/out.
// Round 4:
//  - dego_hist: 25KB LDS, grid 640, int4 loads (was 1 block/CU latency-bound)
//  - agg: planar fp16 half-tables (6.4MB each, closer to 4MB/XCD L2);
//    2 passes/layer, 2 edges per wave-iter, shfl_xor(32) combine
//  - CSR: 128-node ranges (3 blocks/CU in csr), 4B packed bucket entries
// ---------------------------------------------------------------------------

#define WG 256
static constexpr int NCHUNK = 512;   // edge chunks for dst bucketing
static constexpr int RW_SH  = 7;     // range width = 128 nodes (dst>>7)
static constexpr int RWID   = 1 << RW_SH;
static constexpr int BPRO   = 6256;  // bins per range for dego histogram (25KB)
static constexpr int NRO    = 16;    // dego ranges (16*6256 >= 100000)
static constexpr int NCO    = 40;    // edge chunks for dego histogram

__device__ __forceinline__ int block_scan_excl(int v, int tid, int* sd, int& total) {
  sd[tid] = v;
  __syncthreads();
  for (int off = 1; off < 256; off <<= 1) {
    int t = (tid >= off) ? sd[tid - off] : 0;
    __syncthreads();
    sd[tid] += t;
    __syncthreads();
  }
  int incl = sd[tid];
  total = sd[255];
  __syncthreads();
  return incl - v;
}

// --- Pass A: per-chunk coarse histogram over dst ranges ---------------------
__global__ __launch_bounds__(WG) void coarse_hist_kernel(const int* __restrict__ dst,
                                                         int* __restrict__ cntA,
                                                         int NR, int E, int EPC) {
  __shared__ int cnt[1024];
  const int c = blockIdx.x, tid = threadIdx.x;
  for (int i = tid; i < NR; i += WG) cnt[i] = 0;
  __syncthreads();
  const int base = c * EPC;                    // EPC multiple of 4, base aligned
  const int nv4 = EPC >> 2;
  const int4* d4 = (const int4*)(dst + base);
  for (int i = tid; i < nv4; i += WG) {
    const int e = base + (i << 2);
    if (e + 3 < E) {
      const int4 v = d4[i];
      atomicAdd(&cnt[v.x >> RW_SH], 1);
      atomicAdd(&cnt[v.y >> RW_SH], 1);
      atomicAdd(&cnt[v.z >> RW_SH], 1);
      atomicAdd(&cnt[v.w >> RW_SH], 1);
    } else {
      for (int j = 0; j < 4; ++j) {
        const int ee = e + j;
        if (ee < E) atomicAdd(&cnt[dst[ee] >> RW_SH], 1);
      }
    }
  }
  __syncthreads();
  for (int i = tid; i < NR; i += WG) cntA[i * NCHUNK + c] = cnt[i];
}

// --- Pass B1: per-range exclusive scan over the 512 chunks ------------------
__global__ __launch_bounds__(WG) void chunkscan_kernel(const int* __restrict__ cntA,
                                                       int* __restrict__ base_rel,
                                                       int* __restrict__ cntR) {
  __shared__ int sd[256];
  const int r = blockIdx.x, tid = threadIdx.x;
  const int row = r * NCHUNK;
  int t0, t1;
  const int v0 = cntA[row + tid];
  const int e0 = block_scan_excl(v0, tid, sd, t0);
  base_rel[row + tid] = e0;
  const int v1 = cntA[row + 256 + tid];
  const int e1 = block_scan_excl(v1, tid, sd, t1);
  base_rel[row + 256 + tid] = t0 + e1;
  if (tid == 0) cntR[r] = t0 + t1;
}

// --- Pass B2: exclusive scan over up to 1024 ranges -> rangeStart -----------
__global__ __launch_bounds__(WG) void rangescan_kernel(const int* __restrict__ cntR,
                                                       int* __restrict__ rangeStart,
                                                       int* __restrict__ rptr,
                                                       int NR, int N, int E) {
  __shared__ int sd[256];
  const int tid = threadIdx.x;
  int carry = 0;
  for (int base = 0; base < NR; base += 256) {
    const int idx = base + tid;
    const int v = (idx < NR) ? cntR[idx] : 0;
    int tot;
    const int e = block_scan_excl(v, tid, sd, tot);
    if (idx < NR) rangeStart[idx] = carry + e;
    carry += tot;
  }
  if (tid == 0) { rangeStart[NR] = E; rptr[N] = E; }
}

// --- Pass C: bucket scatter with LDS cursors, 4B packed entries -------------
// entry = (src << RW_SH) | (dst & (RWID-1));  src<2^17, RW_SH=7 -> 24 bits
__global__ __launch_bounds__(WG) void bucket_kernel(const int* __restrict__ src,
                                                    const int* __restrict__ dst,
                                                    const int* __restrict__ base_rel,
                                                    const int* __restrict__ rangeStart,
                                                    int* __restrict__ bucket,
                                                    int NR, int E, int EPC) {
  __shared__ int cur[1024];
  const int c = blockIdx.x, tid = threadIdx.x;
  for (int i = tid; i < NR; i += WG) cur[i] = rangeStart[i] + base_rel[i * NCHUNK + c];
  __syncthreads();
  const int base = c * EPC;
  const int nv4 = EPC >> 2;
  const int4* s4 = (const int4*)(src + base);
  const int4* d4 = (const int4*)(dst + base);
  for (int i = tid; i < nv4; i += WG) {
    const int e = base + (i << 2);
    if (e + 3 < E) {
      const int4 sv = s4[i];
      const int4 dv = d4[i];
      int p;
      p = atomicAdd(&cur[dv.x >> RW_SH], 1); bucket[p] = (sv.x << RW_SH) | (dv.x & (RWID - 1));
      p = atomicAdd(&cur[dv.y >> RW_SH], 1); bucket[p] = (sv.y << RW_SH) | (dv.y & (RWID - 1));
      p = atomicAdd(&cur[dv.z >> RW_SH], 1); bucket[p] = (sv.z << RW_SH) | (dv.z & (RWID - 1));
      p = atomicAdd(&cur[dv.w >> RW_SH], 1); bucket[p] = (sv.w << RW_SH) | (dv.w & (RWID - 1));
    } else {
      for (int j = 0; j < 4; ++j) {
        const int ee = e + j;
        if (ee < E) {
          const int s = src[ee], d = dst[ee];
          const int p = atomicAdd(&cur[d >> RW_SH], 1);
          bucket[p] = (s << RW_SH) | (d & (RWID - 1));
        }
      }
    }
  }
}

// --- Pass D: per-range CSR finalize (rptr, degi, esrc) ----------------------
__global__ __launch_bounds__(WG) void csr_kernel(const int* __restrict__ bucket,
                                                 const int* __restrict__ rangeStart,
                                                 int* __restrict__ rptr,
                                                 int* __restrict__ degi,
                                                 int* __restrict__ esrc, int N) {
  __shared__ int hist[RWID], sd[256];
  const int r = blockIdx.x, tid = threadIdx.x;
  const int s0 = rangeStart[r], s1 = rangeStart[r + 1];
  if (tid < RWID) hist[tid] = 0;
  __syncthreads();
  for (int e = s0 + tid; e < s1; e += WG) atomicAdd(&hist[bucket[e] & (RWID - 1)], 1);
  __syncthreads();
  const int v = (tid < RWID) ? hist[tid] : 0;
  int tot;
  const int excl = block_scan_excl(v, tid, sd, tot);
  const int node = (r << RW_SH) + tid;
  if (tid < RWID && node < N) { degi[node] = v; rptr[node] = s0 + excl; }
  if (tid < RWID) hist[tid] = s0 + excl;  // reuse as absolute cursor
  __syncthreads();
  for (int e = s0 + tid; e < s1; e += WG) {
    const int pk = bucket[e];
    const int p = atomicAdd(&hist[pk & (RWID - 1)], 1);
    esrc[p] = pk >> RW_SH;
  }
}

// --- dego: privatized LDS histogram over src, slab + reduce + inv -----------
__global__ __launch_bounds__(WG) void dego_hist_kernel(const int* __restrict__ src,
                                                       int* __restrict__ slab,
                                                       int N, int E, int EPCO) {
  __shared__ int h[BPRO];  // 25 KB
  const int rr = blockIdx.x / NCO, cc = blockIdx.x % NCO;
  const int tid = threadIdx.x;
  for (int i = tid; i < (BPRO >> 2); i += WG) ((int4*)h)[i] = make_int4(0, 0, 0, 0);
  __syncthreads();
  const int lo = rr * BPRO;
  const int base = cc * EPCO;                  // EPCO multiple of 4
  const int nv4 = EPCO >> 2;
  const int4* s4 = (const int4*)(src + base);
  for (int i = tid; i < nv4; i += WG) {
    const int e = base + (i << 2);
    if (e + 3 < E) {
      const int4 v = s4[i];
      unsigned b;
      b = (unsigned)(v.x - lo); if (b < (unsigned)BPRO) atomicAdd(&h[b], 1);
      b = (unsigned)(v.y - lo); if (b < (unsigned)BPRO) atomicAdd(&h[b], 1);
      b = (unsigned)(v.z - lo); if (b < (unsigned)BPRO) atomicAdd(&h[b], 1);
      b = (unsigned)(v.w - lo); if (b < (unsigned)BPRO) atomicAdd(&h[b], 1);
    } else {
      for (int j = 0; j < 4; ++j) {
        const int ee = e + j;
        if (ee < E) {
          const unsigned b = (unsigned)(src[ee] - lo);
          if (b < (unsigned)BPRO) atomicAdd(&h[b], 1);
        }
      }
    }
  }
  __syncthreads();
  int* srow = slab + (size_t)cc * N;
  for (int i = tid; i < (BPRO >> 2); i += WG) {
    const int g = lo + (i << 2);
    if (g + 3 < N) {
      ((int4*)(srow + g))[0] = ((const int4*)h)[i];
    } else {
      for (int j = 0; j < 4; ++j)
        if (g + j < N) srow[g + j] = h[(i << 2) + j];
    }
  }
}

__global__ __launch_bounds__(WG) void dego_reduce_inv_kernel(const int* __restrict__ slab,
                                                             const int* __restrict__ degi,
                                                             float* __restrict__ invo,
                                                             float* __restrict__ invi, int N) {
  const int i = blockIdx.x * WG + threadIdx.x;
  if (i >= N) return;
  int s = 0;
#pragma unroll
  for (int c = 0; c < NCO; ++c) s += slab[(size_t)c * N + i];
  if (s < 1) s = 1;
  int dii = degi[i]; if (dii < 1) dii = 1;
  invo[i] = rsqrtf((float)s);
  invi[i] = rsqrtf((float)dii);
}

// --- dense GEMM -> planar fp16 halves: h0[n][0..31], h1[n][0..31] -----------
template <int K, int TM>
__global__ __launch_bounds__(256) void gemm_planar_kernel(const float* __restrict__ in,
                                                          const float* __restrict__ W,
                                                          const float* __restrict__ rowscale,
                                                          __half* __restrict__ h0,
                                                          __half* __restrict__ h1, int N) {
  constexpr int RPT = TM / 4;
  __shared__ float xs[TM * K];
  __shared__ float wsm[K * 64];
  const int tid = threadIdx.x;
  const int row0 = blockIdx.x * TM;

  for (int i = tid; i < K * 16; i += 256)
    ((float4*)wsm)[i] = ((const float4*)W)[i];

  for (int i = tid; i < TM * K / 4; i += 256) {
    const int fl = i * 4;
    const int r = fl / K;
    const int grow = row0 + r;
    float4 v = make_float4(0.f, 0.f, 0.f, 0.f);
    if (grow < N) {
      v = *(const float4*)(in + (size_t)grow * K + (fl & (K - 1)));
      const float s = rowscale[grow];
      v.x *= s; v.y *= s; v.z *= s; v.w *= s;
    }
    *(float4*)(xs + fl) = v;
  }
  __syncthreads();

  const int c = tid & 63;
  const int rbase = (tid >> 6) * RPT;
  float acc[RPT];
#pragma unroll
  for (int r = 0; r < RPT; ++r) acc[r] = 0.f;

  for (int k = 0; k < K; k += 4) {
    const float w0 = wsm[(k + 0) * 64 + c];
    const float w1 = wsm[(k + 1) * 64 + c];
    const float w2 = wsm[(k + 2) * 64 + c];
    const float w3 = wsm[(k + 3) * 64 + c];
#pragma unroll
    for (int r = 0; r < RPT; ++r) {
      const float4 xv = *(const float4*)(xs + (rbase + r) * K + k);
      acc[r] += xv.x * w0 + xv.y * w1 + xv.z * w2 + xv.w * w3;
    }
  }

  __half* hp = (c < 32) ? h0 : h1;
  const int fc = c & 31;
#pragma unroll
  for (int r = 0; r < RPT; ++r) {
    const int grow = row0 + rbase + r;
    if (grow < N) hp[(size_t)grow * 32 + fc] = __float2half(acc[r]);
  }
}

// --- dense GEMM -> fp32 contiguous (head) -----------------------------------
template <int K, int TM>
__global__ __launch_bounds__(256) void gemm_kernel(const float* __restrict__ in,
                                                   const float* __restrict__ W,
                                                   const float* __restrict__ bias,
                                                   float* __restrict__ out, int N) {
  constexpr int RPT = TM / 4;
  __shared__ float xs[TM * K];
  __shared__ float wsm[K * 64];
  const int tid = threadIdx.x;
  const int row0 = blockIdx.x * TM;

  for (int i = tid; i < K * 16; i += 256)
    ((float4*)wsm)[i] = ((const float4*)W)[i];

  for (int i = tid; i < TM * K / 4; i += 256) {
    const int fl = i * 4;
    const int r = fl / K;
    const int grow = row0 + r;
    float4 v = make_float4(0.f, 0.f, 0.f, 0.f);
    if (grow < N) v = *(const float4*)(in + (size_t)grow * K + (fl & (K - 1)));
    *(float4*)(xs + fl) = v;
  }
  __syncthreads();

  const int c = tid & 63;
  const int rbase = (tid >> 6) * RPT;
  float acc[RPT];
#pragma unroll
  for (int r = 0; r < RPT; ++r) acc[r] = 0.f;

  for (int k = 0; k < K; k += 4) {
    const float w0 = wsm[(k + 0) * 64 + c];
    const float w1 = wsm[(k + 1) * 64 + c];
    const float w2 = wsm[(k + 2) * 64 + c];
    const float w3 = wsm[(k + 3) * 64 + c];
#pragma unroll
    for (int r = 0; r < RPT; ++r) {
      const float4 xv = *(const float4*)(xs + (rbase + r) * K + k);
      acc[r] += xv.x * w0 + xv.y * w1 + xv.z * w2 + xv.w * w3;
    }
  }

  const float bv = bias[c];
#pragma unroll
  for (int r = 0; r < RPT; ++r) {
    const int grow = row0 + rbase + r;
    if (grow < N) out[(size_t)grow * 64 + c] = acc[r] + bv;
  }
}

// --- half-table CSR gather aggregation --------------------------------------
// Wave per node; lanes 0-31 gather edge e, lanes 32-63 edge e+1 (32 features).
// out[n][hoff + f] = elu?(sum * invi[n] + bias[hoff + f])
__global__ __launch_bounds__(256) void agg_half_kernel(const __half* __restrict__ hp,
                                                       const int* __restrict__ rptr,
                                                       const int* __restrict__ esrc,
                                                       const float* __restrict__ invin,
                                                       const float* __restrict__ bias32,
                                                       float* __restrict__ out32, int N,
                                                       int apply_elu) {
  const int w = (blockIdx.x * 256 + threadIdx.x) >> 6;
  const int lane = threadIdx.x & 63;
  const int hs = lane >> 5;   // which edge of the pair
  const int f = lane & 31;    // feature
  if (w >= N) return;
  const int e0 = rptr[w];
  const int e1 = rptr[w + 1];
  float acc = 0.f;
  int e = e0;
  for (; e + 16 <= e1; e += 16) {   // 8 pairs in flight
    int s[8];
#pragma unroll
    for (int j = 0; j < 8; ++j) s[j] = esrc[e + 2 * j + hs];
    float a[8];
#pragma unroll
    for (int j = 0; j < 8; ++j) a[j] = __half2float(hp[(size_t)s[j] * 32 + f]);
    acc += (((a[0] + a[1]) + (a[2] + a[3])) + ((a[4] + a[5]) + (a[6] + a[7])));
  }
  for (; e + 2 <= e1; e += 2)
    acc += __half2float(hp[(size_t)esrc[e + hs] * 32 + f]);
  if (e < e1 && hs == 0)
    acc += __half2float(hp[(size_t)esrc[e] * 32 + f]);
  acc += __shfl_xor(acc, 32);
  if (hs == 0) {
    float v = acc * invin[w] + bias32[f];
    if (apply_elu) v = (v > 0.f) ? v : expm1f(v);
    out32[(size_t)w * 64 + f] = v;
  }
}

extern "C" void kernel_launch(void* const* d_in, const int* in_sizes, int n_in,
                              void* d_out, int out_size, void* d_ws, size_t ws_size,
                              hipStream_t stream) {
  const float* x  = (const float*)d_in[0];
  const int*   src = (const int*)d_in[1];
  const int*   dst = (const int*)d_in[2];
  const float* W0 = (const float*)d_in[3];
  const float* b0 = (const float*)d_in[4];
  const float* W1 = (const float*)d_in[5];
  const float* b1 = (const float*)d_in[6];
  const float* W2 = (const float*)d_in[7];
  const float* b2 = (const float*)d_in[8];
  const float* Wl = (const float*)d_in[9];
  const float* bl = (const float*)d_in[10];

  const int N = in_sizes[0] / 128;
  const int E = in_sizes[1];
  const int NR = (N + RWID - 1) >> RW_SH;
  const int EPC = (((E + NCHUNK - 1) / NCHUNK) + 3) & ~3;
  const int EPCO = (((E + NCO - 1) / NCO) + 3) & ~3;

  int* wsp = (int*)d_ws;
  size_t off = 0;
  auto alloc = [&](size_t n) -> int* {   // 256B-aligned regions
    int* p = wsp + off;
    off += (n + 63) & ~(size_t)63;
    return p;
  };
  int*    degi       = alloc(N);
  float*  invo       = (float*)alloc(N);
  float*  invi       = (float*)alloc(N);
  int*    rptr       = alloc((size_t)N + 1);
  int*    esrc       = alloc(E);
  int*    cntA       = alloc((size_t)NR * NCHUNK);
  int*    base_rel   = alloc((size_t)NR * NCHUNK);
  int*    cntR       = alloc(NR);
  int*    rangeStart = alloc((size_t)NR + 1);
  int*    bucket     = alloc(E);
  int*    slab       = alloc((size_t)NCO * N);
  __half* hP0        = (__half*)alloc((size_t)N * 16);  // N x 32 fp16
  __half* hP1        = (__half*)alloc((size_t)N * 16);
  float*  hA         = (float*)alloc((size_t)N * 64);
  (void)ws_size; (void)n_in; (void)out_size;

  const int gN = (N + WG - 1) / WG;
  const int gAgg = (N + 3) / 4;

  // CSR-by-dst build (atomic-free at global scope)
  coarse_hist_kernel<<<NCHUNK, WG, 0, stream>>>(dst, cntA, NR, E, EPC);
  chunkscan_kernel<<<NR, WG, 0, stream>>>(cntA, base_rel, cntR);
  rangescan_kernel<<<1, WG, 0, stream>>>(cntR, rangeStart, rptr, NR, N, E);
  bucket_kernel<<<NCHUNK, WG, 0, stream>>>(src, dst, base_rel, rangeStart, bucket, NR, E, EPC);
  csr_kernel<<<NR, WG, 0, stream>>>(bucket, rangeStart, rptr, degi, esrc, N);

  // out-degree via privatized LDS histograms + fused inv
  dego_hist_kernel<<<NRO * NCO, WG, 0, stream>>>(src, slab, N, E, EPCO);
  dego_reduce_inv_kernel<<<gN, WG, 0, stream>>>(slab, degi, invo, invi, N);

  // layer 0: (x*invo)@W0 -> agg -> *invi+b0 -> elu
  gemm_planar_kernel<128, 32><<<(N + 31) / 32, 256, 0, stream>>>(x, W0, invo, hP0, hP1, N);
  agg_half_kernel<<<gAgg, 256, 0, stream>>>(hP0, rptr, esrc, invi, b0, hA, N, 1);
  agg_half_kernel<<<gAgg, 256, 0, stream>>>(hP1, rptr, esrc, invi, b0 + 32, hA + 32, N, 1);
  // layer 1
  gemm_planar_kernel<64, 64><<<(N + 63) / 64, 256, 0, stream>>>(hA, W1, invo, hP0, hP1, N);
  agg_half_kernel<<<gAgg, 256, 0, stream>>>(hP0, rptr, esrc, invi, b1, hA, N, 1);
  agg_half_kernel<<<gAgg, 256, 0, stream>>>(hP1, rptr, esrc, invi, b1 + 32, hA + 32, N, 1);
  // layer 2 (+ fused elu ahead of the linear head)
  gemm_planar_kernel<64, 64><<<(N + 63) / 64, 256, 0, stream>>>(hA, W2, invo, hP0, hP1, N);
  agg_half_kernel<<<gAgg, 256, 0, stream>>>(hP0, rptr, esrc, invi, b2, hA, N, 1);
  agg_half_kernel<<<gAgg, 256, 0, stream>>>(hP1, rptr, esrc, invi, b2 + 32, hA + 32, N, 1);
  // head: elu(h2) @ Wl + bl
  gemm_kernel<64, 64><<<(N + 63) / 64, 256, 0, stream>>>(hA, Wl, bl, (float*)d_out, N);
}

// Round 5
// 322.895 us; speedup vs baseline: 1.7496x; 1.7496x over previous
//
#include <hip/hip_runtime.h>
#include <hip/hip_fp16.h>
#include <cstdint>
#include <cstddef>

// ---------------------------------------------------------------------------
// GCN: 3x GraphConv(norm='both') + linear head, fp32 in/out.
// Round 5:
//  - agg reverted to full-row fp16 gather (128B = 1 line per edge; the round-4
//    planar split doubled line traffic)
//  - all 4 GEMMs -> MFMA f32_16x16x32_f16, LDS-free, A loaded per-fragment
//    from global fp32 + in-reg cvt, B from pre-transposed f16 WT (L1-hit)
//  - CSR build + dego histogram unchanged from round 4
// ---------------------------------------------------------------------------

#define WG 256
static constexpr int NCHUNK = 512;   // edge chunks for dst bucketing
static constexpr int RW_SH  = 7;     // range width = 128 nodes (dst>>7)
static constexpr int RWID   = 1 << RW_SH;
static constexpr int BPRO   = 6256;  // bins per range for dego histogram (25KB)
static constexpr int NRO    = 16;    // dego ranges (16*6256 >= 100000)
static constexpr int NCO    = 40;    // edge chunks for dego histogram

typedef _Float16 half8 __attribute__((ext_vector_type(8)));
typedef float f32x4 __attribute__((ext_vector_type(4)));

__device__ __forceinline__ int block_scan_excl(int v, int tid, int* sd, int& total) {
  sd[tid] = v;
  __syncthreads();
  for (int off = 1; off < 256; off <<= 1) {
    int t = (tid >= off) ? sd[tid - off] : 0;
    __syncthreads();
    sd[tid] += t;
    __syncthreads();
  }
  int incl = sd[tid];
  total = sd[255];
  __syncthreads();
  return incl - v;
}

// --- Pass A: per-chunk coarse histogram over dst ranges ---------------------
__global__ __launch_bounds__(WG) void coarse_hist_kernel(const int* __restrict__ dst,
                                                         int* __restrict__ cntA,
                                                         int NR, int E, int EPC) {
  __shared__ int cnt[1024];
  const int c = blockIdx.x, tid = threadIdx.x;
  for (int i = tid; i < NR; i += WG) cnt[i] = 0;
  __syncthreads();
  const int base = c * EPC;
  const int nv4 = EPC >> 2;
  const int4* d4 = (const int4*)(dst + base);
  for (int i = tid; i < nv4; i += WG) {
    const int e = base + (i << 2);
    if (e + 3 < E) {
      const int4 v = d4[i];
      atomicAdd(&cnt[v.x >> RW_SH], 1);
      atomicAdd(&cnt[v.y >> RW_SH], 1);
      atomicAdd(&cnt[v.z >> RW_SH], 1);
      atomicAdd(&cnt[v.w >> RW_SH], 1);
    } else {
      for (int j = 0; j < 4; ++j) {
        const int ee = e + j;
        if (ee < E) atomicAdd(&cnt[dst[ee] >> RW_SH], 1);
      }
    }
  }
  __syncthreads();
  for (int i = tid; i < NR; i += WG) cntA[i * NCHUNK + c] = cnt[i];
}

// --- Pass B1: per-range exclusive scan over the 512 chunks ------------------
__global__ __launch_bounds__(WG) void chunkscan_kernel(const int* __restrict__ cntA,
                                                       int* __restrict__ base_rel,
                                                       int* __restrict__ cntR) {
  __shared__ int sd[256];
  const int r = blockIdx.x, tid = threadIdx.x;
  const int row = r * NCHUNK;
  int t0, t1;
  const int v0 = cntA[row + tid];
  const int e0 = block_scan_excl(v0, tid, sd, t0);
  base_rel[row + tid] = e0;
  const int v1 = cntA[row + 256 + tid];
  const int e1 = block_scan_excl(v1, tid, sd, t1);
  base_rel[row + 256 + tid] = t0 + e1;
  if (tid == 0) cntR[r] = t0 + t1;
}

// --- Pass B2: exclusive scan over up to 1024 ranges -> rangeStart -----------
__global__ __launch_bounds__(WG) void rangescan_kernel(const int* __restrict__ cntR,
                                                       int* __restrict__ rangeStart,
                                                       int* __restrict__ rptr,
                                                       int NR, int N, int E) {
  __shared__ int sd[256];
  const int tid = threadIdx.x;
  int carry = 0;
  for (int base = 0; base < NR; base += 256) {
    const int idx = base + tid;
    const int v = (idx < NR) ? cntR[idx] : 0;
    int tot;
    const int e = block_scan_excl(v, tid, sd, tot);
    if (idx < NR) rangeStart[idx] = carry + e;
    carry += tot;
  }
  if (tid == 0) { rangeStart[NR] = E; rptr[N] = E; }
}

// --- Pass C: bucket scatter with LDS cursors, 4B packed entries -------------
__global__ __launch_bounds__(WG) void bucket_kernel(const int* __restrict__ src,
                                                    const int* __restrict__ dst,
                                                    const int* __restrict__ base_rel,
                                                    const int* __restrict__ rangeStart,
                                                    int* __restrict__ bucket,
                                                    int NR, int E, int EPC) {
  __shared__ int cur[1024];
  const int c = blockIdx.x, tid = threadIdx.x;
  for (int i = tid; i < NR; i += WG) cur[i] = rangeStart[i] + base_rel[i * NCHUNK + c];
  __syncthreads();
  const int base = c * EPC;
  const int nv4 = EPC >> 2;
  const int4* s4 = (const int4*)(src + base);
  const int4* d4 = (const int4*)(dst + base);
  for (int i = tid; i < nv4; i += WG) {
    const int e = base + (i << 2);
    if (e + 3 < E) {
      const int4 sv = s4[i];
      const int4 dv = d4[i];
      int p;
      p = atomicAdd(&cur[dv.x >> RW_SH], 1); bucket[p] = (sv.x << RW_SH) | (dv.x & (RWID - 1));
      p = atomicAdd(&cur[dv.y >> RW_SH], 1); bucket[p] = (sv.y << RW_SH) | (dv.y & (RWID - 1));
      p = atomicAdd(&cur[dv.z >> RW_SH], 1); bucket[p] = (sv.z << RW_SH) | (dv.z & (RWID - 1));
      p = atomicAdd(&cur[dv.w >> RW_SH], 1); bucket[p] = (sv.w << RW_SH) | (dv.w & (RWID - 1));
    } else {
      for (int j = 0; j < 4; ++j) {
        const int ee = e + j;
        if (ee < E) {
          const int s = src[ee], d = dst[ee];
          const int p = atomicAdd(&cur[d >> RW_SH], 1);
          bucket[p] = (s << RW_SH) | (d & (RWID - 1));
        }
      }
    }
  }
}

// --- Pass D: per-range CSR finalize (rptr, degi, esrc) ----------------------
__global__ __launch_bounds__(WG) void csr_kernel(const int* __restrict__ bucket,
                                                 const int* __restrict__ rangeStart,
                                                 int* __restrict__ rptr,
                                                 int* __restrict__ degi,
                                                 int* __restrict__ esrc, int N) {
  __shared__ int hist[RWID], sd[256];
  const int r = blockIdx.x, tid = threadIdx.x;
  const int s0 = rangeStart[r], s1 = rangeStart[r + 1];
  if (tid < RWID) hist[tid] = 0;
  __syncthreads();
  for (int e = s0 + tid; e < s1; e += WG) atomicAdd(&hist[bucket[e] & (RWID - 1)], 1);
  __syncthreads();
  const int v = (tid < RWID) ? hist[tid] : 0;
  int tot;
  const int excl = block_scan_excl(v, tid, sd, tot);
  const int node = (r << RW_SH) + tid;
  if (tid < RWID && node < N) { degi[node] = v; rptr[node] = s0 + excl; }
  if (tid < RWID) hist[tid] = s0 + excl;
  __syncthreads();
  for (int e = s0 + tid; e < s1; e += WG) {
    const int pk = bucket[e];
    const int p = atomicAdd(&hist[pk & (RWID - 1)], 1);
    esrc[p] = pk >> RW_SH;
  }
}

// --- dego: privatized LDS histogram over src, slab + reduce + inv -----------
__global__ __launch_bounds__(WG) void dego_hist_kernel(const int* __restrict__ src,
                                                       int* __restrict__ slab,
                                                       int N, int E, int EPCO) {
  __shared__ int h[BPRO];  // 25 KB
  const int rr = blockIdx.x / NCO, cc = blockIdx.x % NCO;
  const int tid = threadIdx.x;
  for (int i = tid; i < (BPRO >> 2); i += WG) ((int4*)h)[i] = make_int4(0, 0, 0, 0);
  __syncthreads();
  const int lo = rr * BPRO;
  const int base = cc * EPCO;
  const int nv4 = EPCO >> 2;
  const int4* s4 = (const int4*)(src + base);
  for (int i = tid; i < nv4; i += WG) {
    const int e = base + (i << 2);
    if (e + 3 < E) {
      const int4 v = s4[i];
      unsigned b;
      b = (unsigned)(v.x - lo); if (b < (unsigned)BPRO) atomicAdd(&h[b], 1);
      b = (unsigned)(v.y - lo); if (b < (unsigned)BPRO) atomicAdd(&h[b], 1);
      b = (unsigned)(v.z - lo); if (b < (unsigned)BPRO) atomicAdd(&h[b], 1);
      b = (unsigned)(v.w - lo); if (b < (unsigned)BPRO) atomicAdd(&h[b], 1);
    } else {
      for (int j = 0; j < 4; ++j) {
        const int ee = e + j;
        if (ee < E) {
          const unsigned b = (unsigned)(src[ee] - lo);
          if (b < (unsigned)BPRO) atomicAdd(&h[b], 1);
        }
      }
    }
  }
  __syncthreads();
  int* srow = slab + (size_t)cc * N;
  for (int i = tid; i < (BPRO >> 2); i += WG) {
    const int g = lo + (i << 2);
    if (g + 3 < N) {
      ((int4*)(srow + g))[0] = ((const int4*)h)[i];
    } else {
      for (int j = 0; j < 4; ++j)
        if (g + j < N) srow[g + j] = h[(i << 2) + j];
    }
  }
}

__global__ __launch_bounds__(WG) void dego_reduce_inv_kernel(const int* __restrict__ slab,
                                                             const int* __restrict__ degi,
                                                             float* __restrict__ invo,
                                                             float* __restrict__ invi, int N) {
  const int i = blockIdx.x * WG + threadIdx.x;
  if (i >= N) return;
  int s = 0;
#pragma unroll
  for (int c = 0; c < NCO; ++c) s += slab[(size_t)c * N + i];
  if (s < 1) s = 1;
  int dii = degi[i]; if (dii < 1) dii = 1;
  invo[i] = rsqrtf((float)s);
  invi[i] = rsqrtf((float)dii);
}

// --- weight transpose+convert: WT[c][k] = (f16)W[k][c] ----------------------
__global__ __launch_bounds__(WG) void wtrans_kernel(const float* __restrict__ W0,
                                                    const float* __restrict__ W1,
                                                    const float* __restrict__ W2,
                                                    const float* __restrict__ Wl,
                                                    _Float16* __restrict__ T0,
                                                    _Float16* __restrict__ T1,
                                                    _Float16* __restrict__ T2,
                                                    _Float16* __restrict__ Tl) {
  const float* W; _Float16* T; int K;
  switch (blockIdx.x) {
    case 0: W = W0; T = T0; K = 128; break;
    case 1: W = W1; T = T1; K = 64; break;
    case 2: W = W2; T = T2; K = 64; break;
    default: W = Wl; T = Tl; K = 64; break;
  }
  for (int i = threadIdx.x; i < K * 64; i += WG) {
    const int k = i >> 6, c = i & 63;
    T[c * K + k] = (_Float16)W[i];
  }
}

// --- MFMA conv GEMM: hP[r][c] = f16( invo[r] * sum_k in[r][k] W[k][c] ) -----
// 256 thr = 4 waves; block tile 64 rows x 64 cols; wave = 16 rows x 64 cols.
// A-frag: row=lane&15, k=kb+8*(lane>>4)  (fp32 global -> cvt f16, 1 line/row)
// B-frag: col=lane&15, same k, one 16B load from WT[col*K+kb]
// C/D:    col=lane&15, row=(lane>>4)*4+reg   [m89-verified mapping]
template <int K>
__global__ __launch_bounds__(256) void gemm_conv_mfma(const float* __restrict__ in,
                                                      const _Float16* __restrict__ WT,
                                                      const float* __restrict__ invo,
                                                      _Float16* __restrict__ hP, int N) {
  const int tid = threadIdx.x;
  const int w = tid >> 6, l = tid & 63;
  const int rowA = blockIdx.x * 64 + w * 16 + (l & 15);
  const int ar = (rowA < N) ? rowA : (N - 1);
  const int g8 = (l >> 4) * 8;

  f32x4 acc[4];
#pragma unroll
  for (int t = 0; t < 4; ++t) acc[t] = (f32x4){0.f, 0.f, 0.f, 0.f};

#pragma unroll
  for (int s = 0; s < K / 32; ++s) {
    const int kb = s * 32 + g8;
    const float4 f0 = *(const float4*)(in + (size_t)ar * K + kb);
    const float4 f1 = *(const float4*)(in + (size_t)ar * K + kb + 4);
    half8 a;
    a[0] = (_Float16)f0.x; a[1] = (_Float16)f0.y; a[2] = (_Float16)f0.z; a[3] = (_Float16)f0.w;
    a[4] = (_Float16)f1.x; a[5] = (_Float16)f1.y; a[6] = (_Float16)f1.z; a[7] = (_Float16)f1.w;
#pragma unroll
    for (int t = 0; t < 4; ++t) {
      const half8 b = *(const half8*)(WT + (size_t)(16 * t + (l & 15)) * K + kb);
      acc[t] = __builtin_amdgcn_mfma_f32_16x16x32_f16(a, b, acc[t], 0, 0, 0);
    }
  }

  const int rbase = blockIdx.x * 64 + w * 16 + (l >> 4) * 4;
#pragma unroll
  for (int r = 0; r < 4; ++r) {
    const int row = rbase + r;
    if (row < N) {
      const float sc = invo[row];
#pragma unroll
      for (int t = 0; t < 4; ++t)
        hP[(size_t)row * 64 + 16 * t + (l & 15)] = (_Float16)(acc[t][r] * sc);
    }
  }
}

// --- MFMA head GEMM: out[r][c] = sum_k in[r][k] W[k][c] + bias[c] (fp32) ----
__global__ __launch_bounds__(256) void gemm_head_mfma(const float* __restrict__ in,
                                                      const _Float16* __restrict__ WT,
                                                      const float* __restrict__ bias,
                                                      float* __restrict__ out, int N) {
  constexpr int K = 64;
  const int tid = threadIdx.x;
  const int w = tid >> 6, l = tid & 63;
  const int rowA = blockIdx.x * 64 + w * 16 + (l & 15);
  const int ar = (rowA < N) ? rowA : (N - 1);
  const int g8 = (l >> 4) * 8;

  f32x4 acc[4];
#pragma unroll
  for (int t = 0; t < 4; ++t) acc[t] = (f32x4){0.f, 0.f, 0.f, 0.f};

#pragma unroll
  for (int s = 0; s < K / 32; ++s) {
    const int kb = s * 32 + g8;
    const float4 f0 = *(const float4*)(in + (size_t)ar * K + kb);
    const float4 f1 = *(const float4*)(in + (size_t)ar * K + kb + 4);
    half8 a;
    a[0] = (_Float16)f0.x; a[1] = (_Float16)f0.y; a[2] = (_Float16)f0.z; a[3] = (_Float16)f0.w;
    a[4] = (_Float16)f1.x; a[5] = (_Float16)f1.y; a[6] = (_Float16)f1.z; a[7] = (_Float16)f1.w;
#pragma unroll
    for (int t = 0; t < 4; ++t) {
      const half8 b = *(const half8*)(WT + (size_t)(16 * t + (l & 15)) * K + kb);
      acc[t] = __builtin_amdgcn_mfma_f32_16x16x32_f16(a, b, acc[t], 0, 0, 0);
    }
  }

  const int rbase = blockIdx.x * 64 + w * 16 + (l >> 4) * 4;
#pragma unroll
  for (int r = 0; r < 4; ++r) {
    const int row = rbase + r;
    if (row < N) {
#pragma unroll
      for (int t = 0; t < 4; ++t) {
        const int c = 16 * t + (l & 15);
        out[(size_t)row * 64 + c] = acc[t][r] + bias[c];
      }
    }
  }
}

// --- CSR gather aggregation over fp16 rows (128B = one line per edge) -------
__global__ __launch_bounds__(256) void agg_kernel(const _Float16* __restrict__ hp,
                                                  const int* __restrict__ rptr,
                                                  const int* __restrict__ esrc,
                                                  const float* __restrict__ invin,
                                                  const float* __restrict__ bias,
                                                  float* __restrict__ out, int N,
                                                  int apply_elu) {
  const int w = (blockIdx.x * 256 + threadIdx.x) >> 6;  // one wave per dst node
  const int lane = threadIdx.x & 63;
  if (w >= N) return;
  const int e0 = rptr[w];
  const int e1 = rptr[w + 1];
  float acc = 0.f;
  int e = e0;
  for (; e + 16 <= e1; e += 16) {
    int s[16];
#pragma unroll
    for (int j = 0; j < 16; ++j) s[j] = esrc[e + j];
    float a[16];
#pragma unroll
    for (int j = 0; j < 16; ++j) a[j] = (float)hp[(size_t)s[j] * 64 + lane];
    float p0 = ((a[0] + a[1]) + (a[2] + a[3])) + ((a[4] + a[5]) + (a[6] + a[7]));
    float p1 = ((a[8] + a[9]) + (a[10] + a[11])) + ((a[12] + a[13]) + (a[14] + a[15]));
    acc += p0 + p1;
  }
  for (; e + 4 <= e1; e += 4) {
    int s[4];
#pragma unroll
    for (int j = 0; j < 4; ++j) s[j] = esrc[e + j];
    float a[4];
#pragma unroll
    for (int j = 0; j < 4; ++j) a[j] = (float)hp[(size_t)s[j] * 64 + lane];
    acc += (a[0] + a[1]) + (a[2] + a[3]);
  }
  for (; e < e1; ++e) acc += (float)hp[(size_t)esrc[e] * 64 + lane];
  float v = acc * invin[w] + bias[lane];
  if (apply_elu) v = (v > 0.f) ? v : expm1f(v);
  out[(size_t)w * 64 + lane] = v;
}

extern "C" void kernel_launch(void* const* d_in, const int* in_sizes, int n_in,
                              void* d_out, int out_size, void* d_ws, size_t ws_size,
                              hipStream_t stream) {
  const float* x  = (const float*)d_in[0];
  const int*   src = (const int*)d_in[1];
  const int*   dst = (const int*)d_in[2];
  const float* W0 = (const float*)d_in[3];
  const float* b0 = (const float*)d_in[4];
  const float* W1 = (const float*)d_in[5];
  const float* b1 = (const float*)d_in[6];
  const float* W2 = (const float*)d_in[7];
  const float* b2 = (const float*)d_in[8];
  const float* Wl = (const float*)d_in[9];
  const float* bl = (const float*)d_in[10];

  const int N = in_sizes[0] / 128;
  const int E = in_sizes[1];
  const int NR = (N + RWID - 1) >> RW_SH;
  const int EPC = (((E + NCHUNK - 1) / NCHUNK) + 3) & ~3;
  const int EPCO = (((E + NCO - 1) / NCO) + 3) & ~3;

  int* wsp = (int*)d_ws;
  size_t off = 0;
  auto alloc = [&](size_t n) -> int* {   // 256B-aligned regions
    int* p = wsp + off;
    off += (n + 63) & ~(size_t)63;
    return p;
  };
  int*      degi       = alloc(N);
  float*    invo       = (float*)alloc(N);
  float*    invi       = (float*)alloc(N);
  int*      rptr       = alloc((size_t)N + 1);
  int*      esrc       = alloc(E);
  int*      cntA       = alloc((size_t)NR * NCHUNK);
  int*      base_rel   = alloc((size_t)NR * NCHUNK);
  int*      cntR       = alloc(NR);
  int*      rangeStart = alloc((size_t)NR + 1);
  int*      bucket     = alloc(E);
  int*      slab       = alloc((size_t)NCO * N);
  _Float16* hP         = (_Float16*)alloc((size_t)N * 32);  // N x 64 f16
  float*    hA         = (float*)alloc((size_t)N * 64);
  _Float16* WT0        = (_Float16*)alloc(64 * 128 / 2);
  _Float16* WT1        = (_Float16*)alloc(64 * 64 / 2);
  _Float16* WT2        = (_Float16*)alloc(64 * 64 / 2);
  _Float16* WTl        = (_Float16*)alloc(64 * 64 / 2);
  (void)ws_size; (void)n_in; (void)out_size;

  const int gN = (N + WG - 1) / WG;
  const int gAgg = (N + 3) / 4;
  const int gGemm = (N + 63) / 64;

  // CSR-by-dst build (atomic-free at global scope)
  coarse_hist_kernel<<<NCHUNK, WG, 0, stream>>>(dst, cntA, NR, E, EPC);
  chunkscan_kernel<<<NR, WG, 0, stream>>>(cntA, base_rel, cntR);
  rangescan_kernel<<<1, WG, 0, stream>>>(cntR, rangeStart, rptr, NR, N, E);
  bucket_kernel<<<NCHUNK, WG, 0, stream>>>(src, dst, base_rel, rangeStart, bucket, NR, E, EPC);
  csr_kernel<<<NR, WG, 0, stream>>>(bucket, rangeStart, rptr, degi, esrc, N);

  // out-degree via privatized LDS histograms + fused inv; weight transposes
  dego_hist_kernel<<<NRO * NCO, WG, 0, stream>>>(src, slab, N, E, EPCO);
  dego_reduce_inv_kernel<<<gN, WG, 0, stream>>>(slab, degi, invo, invi, N);
  wtrans_kernel<<<4, WG, 0, stream>>>(W0, W1, W2, Wl, WT0, WT1, WT2, WTl);

  // layer 0: (x@W0)*invo -> agg -> *invi+b0 -> elu
  gemm_conv_mfma<128><<<gGemm, 256, 0, stream>>>(x, WT0, invo, hP, N);
  agg_kernel<<<gAgg, 256, 0, stream>>>(hP, rptr, esrc, invi, b0, hA, N, 1);
  // layer 1
  gemm_conv_mfma<64><<<gGemm, 256, 0, stream>>>(hA, WT1, invo, hP, N);
  agg_kernel<<<gAgg, 256, 0, stream>>>(hP, rptr, esrc, invi, b1, hA, N, 1);
  // layer 2 (+ fused elu ahead of the linear head)
  gemm_conv_mfma<64><<<gGemm, 256, 0, stream>>>(hA, WT2, invo, hP, N);
  agg_kernel<<<gAgg, 256, 0, stream>>>(hP, rptr, esrc, invi, b2, hA, N, 1);
  // head: elu(h2) @ Wl + bl
  gemm_head_mfma<<<gGemm, 256, 0, stream>>>(hA, WTl, bl, (float*)d_out, N);
}

// Round 6
// 307.455 us; speedup vs baseline: 1.8375x; 1.0502x over previous
//
#include <hip/hip_runtime.h>
#include <hip/hip_fp16.h>
#include <cstdint>
#include <cstddef>

// ---------------------------------------------------------------------------
// GCN: 3x GraphConv(norm='both') + linear head, fp32 in/out.
// Round 6:
//  - agg: 8 lanes per gathered row (b128 load of 8 f16), 1 wave-load = 8
//    edges; shfl_xor(8/16/32) reduce; f16 output (same rounding point as the
//    GEMM's in-register A cast, so numerically identical, half the traffic)
//  - conv/head GEMMs read f16 activations directly (b128 A-frag, no cvt)
//  - CSR build + dego histogram unchanged from round 5
// ---------------------------------------------------------------------------

#define WG 256
static constexpr int NCHUNK = 512;   // edge chunks for dst bucketing
static constexpr int RW_SH  = 7;     // range width = 128 nodes (dst>>7)
static constexpr int RWID   = 1 << RW_SH;
static constexpr int BPRO   = 6256;  // bins per range for dego histogram (25KB)
static constexpr int NRO    = 16;    // dego ranges (16*6256 >= 100000)
static constexpr int NCO    = 40;    // edge chunks for dego histogram

typedef _Float16 half8 __attribute__((ext_vector_type(8)));
typedef float f32x4 __attribute__((ext_vector_type(4)));

__device__ __forceinline__ int block_scan_excl(int v, int tid, int* sd, int& total) {
  sd[tid] = v;
  __syncthreads();
  for (int off = 1; off < 256; off <<= 1) {
    int t = (tid >= off) ? sd[tid - off] : 0;
    __syncthreads();
    sd[tid] += t;
    __syncthreads();
  }
  int incl = sd[tid];
  total = sd[255];
  __syncthreads();
  return incl - v;
}

// --- Pass A: per-chunk coarse histogram over dst ranges ---------------------
__global__ __launch_bounds__(WG) void coarse_hist_kernel(const int* __restrict__ dst,
                                                         int* __restrict__ cntA,
                                                         int NR, int E, int EPC) {
  __shared__ int cnt[1024];
  const int c = blockIdx.x, tid = threadIdx.x;
  for (int i = tid; i < NR; i += WG) cnt[i] = 0;
  __syncthreads();
  const int base = c * EPC;
  const int nv4 = EPC >> 2;
  const int4* d4 = (const int4*)(dst + base);
  for (int i = tid; i < nv4; i += WG) {
    const int e = base + (i << 2);
    if (e + 3 < E) {
      const int4 v = d4[i];
      atomicAdd(&cnt[v.x >> RW_SH], 1);
      atomicAdd(&cnt[v.y >> RW_SH], 1);
      atomicAdd(&cnt[v.z >> RW_SH], 1);
      atomicAdd(&cnt[v.w >> RW_SH], 1);
    } else {
      for (int j = 0; j < 4; ++j) {
        const int ee = e + j;
        if (ee < E) atomicAdd(&cnt[dst[ee] >> RW_SH], 1);
      }
    }
  }
  __syncthreads();
  for (int i = tid; i < NR; i += WG) cntA[i * NCHUNK + c] = cnt[i];
}

// --- Pass B1: per-range exclusive scan over the 512 chunks ------------------
__global__ __launch_bounds__(WG) void chunkscan_kernel(const int* __restrict__ cntA,
                                                       int* __restrict__ base_rel,
                                                       int* __restrict__ cntR) {
  __shared__ int sd[256];
  const int r = blockIdx.x, tid = threadIdx.x;
  const int row = r * NCHUNK;
  int t0, t1;
  const int v0 = cntA[row + tid];
  const int e0 = block_scan_excl(v0, tid, sd, t0);
  base_rel[row + tid] = e0;
  const int v1 = cntA[row + 256 + tid];
  const int e1 = block_scan_excl(v1, tid, sd, t1);
  base_rel[row + 256 + tid] = t0 + e1;
  if (tid == 0) cntR[r] = t0 + t1;
}

// --- Pass B2: exclusive scan over up to 1024 ranges -> rangeStart -----------
__global__ __launch_bounds__(WG) void rangescan_kernel(const int* __restrict__ cntR,
                                                       int* __restrict__ rangeStart,
                                                       int* __restrict__ rptr,
                                                       int NR, int N, int E) {
  __shared__ int sd[256];
  const int tid = threadIdx.x;
  int carry = 0;
  for (int base = 0; base < NR; base += 256) {
    const int idx = base + tid;
    const int v = (idx < NR) ? cntR[idx] : 0;
    int tot;
    const int e = block_scan_excl(v, tid, sd, tot);
    if (idx < NR) rangeStart[idx] = carry + e;
    carry += tot;
  }
  if (tid == 0) { rangeStart[NR] = E; rptr[N] = E; }
}

// --- Pass C: bucket scatter with LDS cursors, 4B packed entries -------------
__global__ __launch_bounds__(WG) void bucket_kernel(const int* __restrict__ src,
                                                    const int* __restrict__ dst,
                                                    const int* __restrict__ base_rel,
                                                    const int* __restrict__ rangeStart,
                                                    int* __restrict__ bucket,
                                                    int NR, int E, int EPC) {
  __shared__ int cur[1024];
  const int c = blockIdx.x, tid = threadIdx.x;
  for (int i = tid; i < NR; i += WG) cur[i] = rangeStart[i] + base_rel[i * NCHUNK + c];
  __syncthreads();
  const int base = c * EPC;
  const int nv4 = EPC >> 2;
  const int4* s4 = (const int4*)(src + base);
  const int4* d4 = (const int4*)(dst + base);
  for (int i = tid; i < nv4; i += WG) {
    const int e = base + (i << 2);
    if (e + 3 < E) {
      const int4 sv = s4[i];
      const int4 dv = d4[i];
      int p;
      p = atomicAdd(&cur[dv.x >> RW_SH], 1); bucket[p] = (sv.x << RW_SH) | (dv.x & (RWID - 1));
      p = atomicAdd(&cur[dv.y >> RW_SH], 1); bucket[p] = (sv.y << RW_SH) | (dv.y & (RWID - 1));
      p = atomicAdd(&cur[dv.z >> RW_SH], 1); bucket[p] = (sv.z << RW_SH) | (dv.z & (RWID - 1));
      p = atomicAdd(&cur[dv.w >> RW_SH], 1); bucket[p] = (sv.w << RW_SH) | (dv.w & (RWID - 1));
    } else {
      for (int j = 0; j < 4; ++j) {
        const int ee = e + j;
        if (ee < E) {
          const int s = src[ee], d = dst[ee];
          const int p = atomicAdd(&cur[d >> RW_SH], 1);
          bucket[p] = (s << RW_SH) | (d & (RWID - 1));
        }
      }
    }
  }
}

// --- Pass D: per-range CSR finalize (rptr, degi, esrc) ----------------------
__global__ __launch_bounds__(WG) void csr_kernel(const int* __restrict__ bucket,
                                                 const int* __restrict__ rangeStart,
                                                 int* __restrict__ rptr,
                                                 int* __restrict__ degi,
                                                 int* __restrict__ esrc, int N) {
  __shared__ int hist[RWID], sd[256];
  const int r = blockIdx.x, tid = threadIdx.x;
  const int s0 = rangeStart[r], s1 = rangeStart[r + 1];
  if (tid < RWID) hist[tid] = 0;
  __syncthreads();
  for (int e = s0 + tid; e < s1; e += WG) atomicAdd(&hist[bucket[e] & (RWID - 1)], 1);
  __syncthreads();
  const int v = (tid < RWID) ? hist[tid] : 0;
  int tot;
  const int excl = block_scan_excl(v, tid, sd, tot);
  const int node = (r << RW_SH) + tid;
  if (tid < RWID && node < N) { degi[node] = v; rptr[node] = s0 + excl; }
  if (tid < RWID) hist[tid] = s0 + excl;
  __syncthreads();
  for (int e = s0 + tid; e < s1; e += WG) {
    const int pk = bucket[e];
    const int p = atomicAdd(&hist[pk & (RWID - 1)], 1);
    esrc[p] = pk >> RW_SH;
  }
}

// --- dego: privatized LDS histogram over src, slab + reduce + inv -----------
__global__ __launch_bounds__(WG) void dego_hist_kernel(const int* __restrict__ src,
                                                       int* __restrict__ slab,
                                                       int N, int E, int EPCO) {
  __shared__ int h[BPRO];  // 25 KB
  const int rr = blockIdx.x / NCO, cc = blockIdx.x % NCO;
  const int tid = threadIdx.x;
  for (int i = tid; i < (BPRO >> 2); i += WG) ((int4*)h)[i] = make_int4(0, 0, 0, 0);
  __syncthreads();
  const int lo = rr * BPRO;
  const int base = cc * EPCO;
  const int nv4 = EPCO >> 2;
  const int4* s4 = (const int4*)(src + base);
  for (int i = tid; i < nv4; i += WG) {
    const int e = base + (i << 2);
    if (e + 3 < E) {
      const int4 v = s4[i];
      unsigned b;
      b = (unsigned)(v.x - lo); if (b < (unsigned)BPRO) atomicAdd(&h[b], 1);
      b = (unsigned)(v.y - lo); if (b < (unsigned)BPRO) atomicAdd(&h[b], 1);
      b = (unsigned)(v.z - lo); if (b < (unsigned)BPRO) atomicAdd(&h[b], 1);
      b = (unsigned)(v.w - lo); if (b < (unsigned)BPRO) atomicAdd(&h[b], 1);
    } else {
      for (int j = 0; j < 4; ++j) {
        const int ee = e + j;
        if (ee < E) {
          const unsigned b = (unsigned)(src[ee] - lo);
          if (b < (unsigned)BPRO) atomicAdd(&h[b], 1);
        }
      }
    }
  }
  __syncthreads();
  int* srow = slab + (size_t)cc * N;
  for (int i = tid; i < (BPRO >> 2); i += WG) {
    const int g = lo + (i << 2);
    if (g + 3 < N) {
      ((int4*)(srow + g))[0] = ((const int4*)h)[i];
    } else {
      for (int j = 0; j < 4; ++j)
        if (g + j < N) srow[g + j] = h[(i << 2) + j];
    }
  }
}

__global__ __launch_bounds__(WG) void dego_reduce_inv_kernel(const int* __restrict__ slab,
                                                             const int* __restrict__ degi,
                                                             float* __restrict__ invo,
                                                             float* __restrict__ invi, int N) {
  const int i = blockIdx.x * WG + threadIdx.x;
  if (i >= N) return;
  int s = 0;
#pragma unroll
  for (int c = 0; c < NCO; ++c) s += slab[(size_t)c * N + i];
  if (s < 1) s = 1;
  int dii = degi[i]; if (dii < 1) dii = 1;
  invo[i] = rsqrtf((float)s);
  invi[i] = rsqrtf((float)dii);
}

// --- weight transpose+convert: WT[c][k] = (f16)W[k][c] ----------------------
__global__ __launch_bounds__(WG) void wtrans_kernel(const float* __restrict__ W0,
                                                    const float* __restrict__ W1,
                                                    const float* __restrict__ W2,
                                                    const float* __restrict__ Wl,
                                                    _Float16* __restrict__ T0,
                                                    _Float16* __restrict__ T1,
                                                    _Float16* __restrict__ T2,
                                                    _Float16* __restrict__ Tl) {
  const float* W; _Float16* T; int K;
  switch (blockIdx.x) {
    case 0: W = W0; T = T0; K = 128; break;
    case 1: W = W1; T = T1; K = 64; break;
    case 2: W = W2; T = T2; K = 64; break;
    default: W = Wl; T = Tl; K = 64; break;
  }
  for (int i = threadIdx.x; i < K * 64; i += WG) {
    const int k = i >> 6, c = i & 63;
    T[c * K + k] = (_Float16)W[i];
  }
}

// --- MFMA conv GEMM: hP[r][c] = f16( invo[r] * sum_k in[r][k] W[k][c] ) -----
// 256 thr = 4 waves; block tile 64 rows x 64 cols; wave = 16 rows x 64 cols.
// A-frag: row=lane&15, k=kb+8*(lane>>4); f32 path: 2x float4 + cvt; f16 path:
// one b128 load. B-frag: one 16B load from WT. C/D: col=lane&15,
// row=(lane>>4)*4+reg [m89-verified mapping]
template <int K, bool F16IN>
__global__ __launch_bounds__(256) void gemm_conv_mfma(const void* __restrict__ inv_,
                                                      const _Float16* __restrict__ WT,
                                                      const float* __restrict__ invo,
                                                      _Float16* __restrict__ hP, int N) {
  const int tid = threadIdx.x;
  const int w = tid >> 6, l = tid & 63;
  const int rowA = blockIdx.x * 64 + w * 16 + (l & 15);
  const int ar = (rowA < N) ? rowA : (N - 1);
  const int g8 = (l >> 4) * 8;

  f32x4 acc[4];
#pragma unroll
  for (int t = 0; t < 4; ++t) acc[t] = (f32x4){0.f, 0.f, 0.f, 0.f};

#pragma unroll
  for (int s = 0; s < K / 32; ++s) {
    const int kb = s * 32 + g8;
    half8 a;
    if constexpr (F16IN) {
      a = *(const half8*)((const _Float16*)inv_ + (size_t)ar * K + kb);
    } else {
      const float* in = (const float*)inv_;
      const float4 f0 = *(const float4*)(in + (size_t)ar * K + kb);
      const float4 f1 = *(const float4*)(in + (size_t)ar * K + kb + 4);
      a[0] = (_Float16)f0.x; a[1] = (_Float16)f0.y; a[2] = (_Float16)f0.z; a[3] = (_Float16)f0.w;
      a[4] = (_Float16)f1.x; a[5] = (_Float16)f1.y; a[6] = (_Float16)f1.z; a[7] = (_Float16)f1.w;
    }
#pragma unroll
    for (int t = 0; t < 4; ++t) {
      const half8 b = *(const half8*)(WT + (size_t)(16 * t + (l & 15)) * K + kb);
      acc[t] = __builtin_amdgcn_mfma_f32_16x16x32_f16(a, b, acc[t], 0, 0, 0);
    }
  }

  const int rbase = blockIdx.x * 64 + w * 16 + (l >> 4) * 4;
#pragma unroll
  for (int r = 0; r < 4; ++r) {
    const int row = rbase + r;
    if (row < N) {
      const float sc = invo[row];
#pragma unroll
      for (int t = 0; t < 4; ++t)
        hP[(size_t)row * 64 + 16 * t + (l & 15)] = (_Float16)(acc[t][r] * sc);
    }
  }
}

// --- MFMA head GEMM (f16 in): out[r][c] = sum_k in[r][k] W[k][c] + bias[c] --
__global__ __launch_bounds__(256) void gemm_head_mfma(const _Float16* __restrict__ in,
                                                      const _Float16* __restrict__ WT,
                                                      const float* __restrict__ bias,
                                                      float* __restrict__ out, int N) {
  constexpr int K = 64;
  const int tid = threadIdx.x;
  const int w = tid >> 6, l = tid & 63;
  const int rowA = blockIdx.x * 64 + w * 16 + (l & 15);
  const int ar = (rowA < N) ? rowA : (N - 1);
  const int g8 = (l >> 4) * 8;

  f32x4 acc[4];
#pragma unroll
  for (int t = 0; t < 4; ++t) acc[t] = (f32x4){0.f, 0.f, 0.f, 0.f};

#pragma unroll
  for (int s = 0; s < K / 32; ++s) {
    const int kb = s * 32 + g8;
    const half8 a = *(const half8*)(in + (size_t)ar * K + kb);
#pragma unroll
    for (int t = 0; t < 4; ++t) {
      const half8 b = *(const half8*)(WT + (size_t)(16 * t + (l & 15)) * K + kb);
      acc[t] = __builtin_amdgcn_mfma_f32_16x16x32_f16(a, b, acc[t], 0, 0, 0);
    }
  }

  const int rbase = blockIdx.x * 64 + w * 16 + (l >> 4) * 4;
#pragma unroll
  for (int r = 0; r < 4; ++r) {
    const int row = rbase + r;
    if (row < N) {
#pragma unroll
      for (int t = 0; t < 4; ++t) {
        const int c = 16 * t + (l & 15);
        out[(size_t)row * 64 + c] = acc[t][r] + bias[c];
      }
    }
  }
}

// --- CSR gather aggregation, 8 lanes per row --------------------------------
// lane = 8*g + f8; lane loads hp[src*64 + f8*8 .. +8] (b128 = 8 f16); wave
// covers 8 edges/load. shfl_xor(8/16/32) reduce over g. f16 output.
__global__ __launch_bounds__(256) void agg_kernel(const _Float16* __restrict__ hp,
                                                  const int* __restrict__ rptr,
                                                  const int* __restrict__ esrc,
                                                  const float* __restrict__ invin,
                                                  const float* __restrict__ bias,
                                                  _Float16* __restrict__ out, int N,
                                                  int apply_elu) {
  const int w = (blockIdx.x * 256 + threadIdx.x) >> 6;  // one wave per dst node
  const int lane = threadIdx.x & 63;
  const int g = lane >> 3;     // edge slot 0..7
  const int f8 = lane & 7;     // feature octet
  if (w >= N) return;
  const int e0 = rptr[w];
  const int e1 = rptr[w + 1];

  float acc[8];
#pragma unroll
  for (int k = 0; k < 8; ++k) acc[k] = 0.f;

  int e = e0;
  for (; e + 16 <= e1; e += 16) {   // 2 groups in flight
    const int sA = esrc[e + g];
    const int sB = esrc[e + 8 + g];
    const half8 hA8 = *(const half8*)(hp + (size_t)sA * 64 + f8 * 8);
    const half8 hB8 = *(const half8*)(hp + (size_t)sB * 64 + f8 * 8);
#pragma unroll
    for (int k = 0; k < 8; ++k) acc[k] += (float)hA8[k] + (float)hB8[k];
  }
  for (; e + 8 <= e1; e += 8) {
    const int s = esrc[e + g];
    const half8 hv = *(const half8*)(hp + (size_t)s * 64 + f8 * 8);
#pragma unroll
    for (int k = 0; k < 8; ++k) acc[k] += (float)hv[k];
  }
  if (e < e1) {                      // masked tail group
    const int rem = e1 - e;
    int idx = e + g; if (idx > e1 - 1) idx = e1 - 1;
    const int s = esrc[idx];
    const half8 hv = *(const half8*)(hp + (size_t)s * 64 + f8 * 8);
    const float m = (g < rem) ? 1.f : 0.f;
#pragma unroll
    for (int k = 0; k < 8; ++k) acc[k] = fmaf(m, (float)hv[k], acc[k]);
  }

  // reduce across the 8 edge slots (g), preserving f8
#pragma unroll
  for (int d = 8; d < 64; d <<= 1) {
#pragma unroll
    for (int k = 0; k < 8; ++k) acc[k] += __shfl_xor(acc[k], d);
  }

  if (g == 0) {   // lanes 0..7 write features f8*8..f8*8+7
    const float vi = invin[w];
    const float4 bv0 = *(const float4*)(bias + f8 * 8);
    const float4 bv1 = *(const float4*)(bias + f8 * 8 + 4);
    const float bb[8] = {bv0.x, bv0.y, bv0.z, bv0.w, bv1.x, bv1.y, bv1.z, bv1.w};
    half8 o;
#pragma unroll
    for (int k = 0; k < 8; ++k) {
      float v = acc[k] * vi + bb[k];
      if (apply_elu) v = (v > 0.f) ? v : expm1f(v);
      o[k] = (_Float16)v;
    }
    *(half8*)(out + (size_t)w * 64 + f8 * 8) = o;
  }
}

extern "C" void kernel_launch(void* const* d_in, const int* in_sizes, int n_in,
                              void* d_out, int out_size, void* d_ws, size_t ws_size,
                              hipStream_t stream) {
  const float* x  = (const float*)d_in[0];
  const int*   src = (const int*)d_in[1];
  const int*   dst = (const int*)d_in[2];
  const float* W0 = (const float*)d_in[3];
  const float* b0 = (const float*)d_in[4];
  const float* W1 = (const float*)d_in[5];
  const float* b1 = (const float*)d_in[6];
  const float* W2 = (const float*)d_in[7];
  const float* b2 = (const float*)d_in[8];
  const float* Wl = (const float*)d_in[9];
  const float* bl = (const float*)d_in[10];

  const int N = in_sizes[0] / 128;
  const int E = in_sizes[1];
  const int NR = (N + RWID - 1) >> RW_SH;
  const int EPC = (((E + NCHUNK - 1) / NCHUNK) + 3) & ~3;
  const int EPCO = (((E + NCO - 1) / NCO) + 3) & ~3;

  int* wsp = (int*)d_ws;
  size_t off = 0;
  auto alloc = [&](size_t n) -> int* {   // 256B-aligned regions
    int* p = wsp + off;
    off += (n + 63) & ~(size_t)63;
    return p;
  };
  int*      degi       = alloc(N);
  float*    invo       = (float*)alloc(N);
  float*    invi       = (float*)alloc(N);
  int*      rptr       = alloc((size_t)N + 1);
  int*      esrc       = alloc(E);
  int*      cntA       = alloc((size_t)NR * NCHUNK);
  int*      base_rel   = alloc((size_t)NR * NCHUNK);
  int*      cntR       = alloc(NR);
  int*      rangeStart = alloc((size_t)NR + 1);
  int*      bucket     = alloc(E);
  int*      slab       = alloc((size_t)NCO * N);
  _Float16* hP         = (_Float16*)alloc((size_t)N * 32);  // N x 64 f16
  _Float16* hA         = (_Float16*)alloc((size_t)N * 32);  // N x 64 f16
  _Float16* WT0        = (_Float16*)alloc(64 * 128 / 2);
  _Float16* WT1        = (_Float16*)alloc(64 * 64 / 2);
  _Float16* WT2        = (_Float16*)alloc(64 * 64 / 2);
  _Float16* WTl        = (_Float16*)alloc(64 * 64 / 2);
  (void)ws_size; (void)n_in; (void)out_size;

  const int gN = (N + WG - 1) / WG;
  const int gAgg = (N + 3) / 4;
  const int gGemm = (N + 63) / 64;

  // CSR-by-dst build (atomic-free at global scope)
  coarse_hist_kernel<<<NCHUNK, WG, 0, stream>>>(dst, cntA, NR, E, EPC);
  chunkscan_kernel<<<NR, WG, 0, stream>>>(cntA, base_rel, cntR);
  rangescan_kernel<<<1, WG, 0, stream>>>(cntR, rangeStart, rptr, NR, N, E);
  bucket_kernel<<<NCHUNK, WG, 0, stream>>>(src, dst, base_rel, rangeStart, bucket, NR, E, EPC);
  csr_kernel<<<NR, WG, 0, stream>>>(bucket, rangeStart, rptr, degi, esrc, N);

  // out-degree via privatized LDS histograms + fused inv; weight transposes
  dego_hist_kernel<<<NRO * NCO, WG, 0, stream>>>(src, slab, N, E, EPCO);
  dego_reduce_inv_kernel<<<gN, WG, 0, stream>>>(slab, degi, invo, invi, N);
  wtrans_kernel<<<4, WG, 0, stream>>>(W0, W1, W2, Wl, WT0, WT1, WT2, WTl);

  // layer 0: (x@W0)*invo -> agg -> *invi+b0 -> elu
  gemm_conv_mfma<128, false><<<gGemm, 256, 0, stream>>>(x, WT0, invo, hP, N);
  agg_kernel<<<gAgg, 256, 0, stream>>>(hP, rptr, esrc, invi, b0, hA, N, 1);
  // layer 1
  gemm_conv_mfma<64, true><<<gGemm, 256, 0, stream>>>(hA, WT1, invo, hP, N);
  agg_kernel<<<gAgg, 256, 0, stream>>>(hP, rptr, esrc, invi, b1, hA, N, 1);
  // layer 2 (+ fused elu ahead of the linear head)
  gemm_conv_mfma<64, true><<<gGemm, 256, 0, stream>>>(hA, WT2, invo, hP, N);
  agg_kernel<<<gAgg, 256, 0, stream>>>(hP, rptr, esrc, invi, b2, hA, N, 1);
  // head: elu(h2) @ Wl + bl
  gemm_head_mfma<<<gGemm, 256, 0, stream>>>(hA, WTl, bl, (float*)d_out, N);
}

// Round 7
// 271.372 us; speedup vs baseline: 2.0818x; 1.1330x over previous
//
#include <hip/hip_runtime.h>
#include <hip/hip_fp16.h>
#include <cstdint>
#include <cstddef>

// ---------------------------------------------------------------------------
// GCN: 3x GraphConv(norm='both') + linear head, fp32 in/out.
// Round 7:
//  - agg epilogue re-parallelized: after butterfly reduce, lane (g,f8) muxes
//    acc[g] (7 cndmask static tree) and handles feature f8*8+g alone; ELU via
//    __expf. (Round 6 ran 8 expm1f serially on 1/8 of lanes -> VALU-bound.)
//  - rest unchanged: 8-lane-per-row b128 gather, MFMA GEMMs, atomic-free CSR.
// ---------------------------------------------------------------------------

#define WG 256
static constexpr int NCHUNK = 512;   // edge chunks for dst bucketing
static constexpr int RW_SH  = 7;     // range width = 128 nodes (dst>>7)
static constexpr int RWID   = 1 << RW_SH;
static constexpr int BPRO   = 6256;  // bins per range for dego histogram (25KB)
static constexpr int NRO    = 16;    // dego ranges (16*6256 >= 100000)
static constexpr int NCO    = 40;    // edge chunks for dego histogram

typedef _Float16 half8 __attribute__((ext_vector_type(8)));
typedef float f32x4 __attribute__((ext_vector_type(4)));

__device__ __forceinline__ int block_scan_excl(int v, int tid, int* sd, int& total) {
  sd[tid] = v;
  __syncthreads();
  for (int off = 1; off < 256; off <<= 1) {
    int t = (tid >= off) ? sd[tid - off] : 0;
    __syncthreads();
    sd[tid] += t;
    __syncthreads();
  }
  int incl = sd[tid];
  total = sd[255];
  __syncthreads();
  return incl - v;
}

// --- Pass A: per-chunk coarse histogram over dst ranges ---------------------
__global__ __launch_bounds__(WG) void coarse_hist_kernel(const int* __restrict__ dst,
                                                         int* __restrict__ cntA,
                                                         int NR, int E, int EPC) {
  __shared__ int cnt[1024];
  const int c = blockIdx.x, tid = threadIdx.x;
  for (int i = tid; i < NR; i += WG) cnt[i] = 0;
  __syncthreads();
  const int base = c * EPC;
  const int nv4 = EPC >> 2;
  const int4* d4 = (const int4*)(dst + base);
  for (int i = tid; i < nv4; i += WG) {
    const int e = base + (i << 2);
    if (e + 3 < E) {
      const int4 v = d4[i];
      atomicAdd(&cnt[v.x >> RW_SH], 1);
      atomicAdd(&cnt[v.y >> RW_SH], 1);
      atomicAdd(&cnt[v.z >> RW_SH], 1);
      atomicAdd(&cnt[v.w >> RW_SH], 1);
    } else {
      for (int j = 0; j < 4; ++j) {
        const int ee = e + j;
        if (ee < E) atomicAdd(&cnt[dst[ee] >> RW_SH], 1);
      }
    }
  }
  __syncthreads();
  for (int i = tid; i < NR; i += WG) cntA[i * NCHUNK + c] = cnt[i];
}

// --- Pass B1: per-range exclusive scan over the 512 chunks ------------------
__global__ __launch_bounds__(WG) void chunkscan_kernel(const int* __restrict__ cntA,
                                                       int* __restrict__ base_rel,
                                                       int* __restrict__ cntR) {
  __shared__ int sd[256];
  const int r = blockIdx.x, tid = threadIdx.x;
  const int row = r * NCHUNK;
  int t0, t1;
  const int v0 = cntA[row + tid];
  const int e0 = block_scan_excl(v0, tid, sd, t0);
  base_rel[row + tid] = e0;
  const int v1 = cntA[row + 256 + tid];
  const int e1 = block_scan_excl(v1, tid, sd, t1);
  base_rel[row + 256 + tid] = t0 + e1;
  if (tid == 0) cntR[r] = t0 + t1;
}

// --- Pass B2: exclusive scan over up to 1024 ranges -> rangeStart -----------
__global__ __launch_bounds__(WG) void rangescan_kernel(const int* __restrict__ cntR,
                                                       int* __restrict__ rangeStart,
                                                       int* __restrict__ rptr,
                                                       int NR, int N, int E) {
  __shared__ int sd[256];
  const int tid = threadIdx.x;
  int carry = 0;
  for (int base = 0; base < NR; base += 256) {
    const int idx = base + tid;
    const int v = (idx < NR) ? cntR[idx] : 0;
    int tot;
    const int e = block_scan_excl(v, tid, sd, tot);
    if (idx < NR) rangeStart[idx] = carry + e;
    carry += tot;
  }
  if (tid == 0) { rangeStart[NR] = E; rptr[N] = E; }
}

// --- Pass C: bucket scatter with LDS cursors, 4B packed entries -------------
__global__ __launch_bounds__(WG) void bucket_kernel(const int* __restrict__ src,
                                                    const int* __restrict__ dst,
                                                    const int* __restrict__ base_rel,
                                                    const int* __restrict__ rangeStart,
                                                    int* __restrict__ bucket,
                                                    int NR, int E, int EPC) {
  __shared__ int cur[1024];
  const int c = blockIdx.x, tid = threadIdx.x;
  for (int i = tid; i < NR; i += WG) cur[i] = rangeStart[i] + base_rel[i * NCHUNK + c];
  __syncthreads();
  const int base = c * EPC;
  const int nv4 = EPC >> 2;
  const int4* s4 = (const int4*)(src + base);
  const int4* d4 = (const int4*)(dst + base);
  for (int i = tid; i < nv4; i += WG) {
    const int e = base + (i << 2);
    if (e + 3 < E) {
      const int4 sv = s4[i];
      const int4 dv = d4[i];
      int p;
      p = atomicAdd(&cur[dv.x >> RW_SH], 1); bucket[p] = (sv.x << RW_SH) | (dv.x & (RWID - 1));
      p = atomicAdd(&cur[dv.y >> RW_SH], 1); bucket[p] = (sv.y << RW_SH) | (dv.y & (RWID - 1));
      p = atomicAdd(&cur[dv.z >> RW_SH], 1); bucket[p] = (sv.z << RW_SH) | (dv.z & (RWID - 1));
      p = atomicAdd(&cur[dv.w >> RW_SH], 1); bucket[p] = (sv.w << RW_SH) | (dv.w & (RWID - 1));
    } else {
      for (int j = 0; j < 4; ++j) {
        const int ee = e + j;
        if (ee < E) {
          const int s = src[ee], d = dst[ee];
          const int p = atomicAdd(&cur[d >> RW_SH], 1);
          bucket[p] = (s << RW_SH) | (d & (RWID - 1));
        }
      }
    }
  }
}

// --- Pass D: per-range CSR finalize (rptr, degi, esrc) ----------------------
__global__ __launch_bounds__(WG) void csr_kernel(const int* __restrict__ bucket,
                                                 const int* __restrict__ rangeStart,
                                                 int* __restrict__ rptr,
                                                 int* __restrict__ degi,
                                                 int* __restrict__ esrc, int N) {
  __shared__ int hist[RWID], sd[256];
  const int r = blockIdx.x, tid = threadIdx.x;
  const int s0 = rangeStart[r], s1 = rangeStart[r + 1];
  if (tid < RWID) hist[tid] = 0;
  __syncthreads();
  for (int e = s0 + tid; e < s1; e += WG) atomicAdd(&hist[bucket[e] & (RWID - 1)], 1);
  __syncthreads();
  const int v = (tid < RWID) ? hist[tid] : 0;
  int tot;
  const int excl = block_scan_excl(v, tid, sd, tot);
  const int node = (r << RW_SH) + tid;
  if (tid < RWID && node < N) { degi[node] = v; rptr[node] = s0 + excl; }
  if (tid < RWID) hist[tid] = s0 + excl;
  __syncthreads();
  for (int e = s0 + tid; e < s1; e += WG) {
    const int pk = bucket[e];
    const int p = atomicAdd(&hist[pk & (RWID - 1)], 1);
    esrc[p] = pk >> RW_SH;
  }
}

// --- dego: privatized LDS histogram over src, slab + reduce + inv -----------
__global__ __launch_bounds__(WG) void dego_hist_kernel(const int* __restrict__ src,
                                                       int* __restrict__ slab,
                                                       int N, int E, int EPCO) {
  __shared__ int h[BPRO];  // 25 KB
  const int rr = blockIdx.x / NCO, cc = blockIdx.x % NCO;
  const int tid = threadIdx.x;
  for (int i = tid; i < (BPRO >> 2); i += WG) ((int4*)h)[i] = make_int4(0, 0, 0, 0);
  __syncthreads();
  const int lo = rr * BPRO;
  const int base = cc * EPCO;
  const int nv4 = EPCO >> 2;
  const int4* s4 = (const int4*)(src + base);
  for (int i = tid; i < nv4; i += WG) {
    const int e = base + (i << 2);
    if (e + 3 < E) {
      const int4 v = s4[i];
      unsigned b;
      b = (unsigned)(v.x - lo); if (b < (unsigned)BPRO) atomicAdd(&h[b], 1);
      b = (unsigned)(v.y - lo); if (b < (unsigned)BPRO) atomicAdd(&h[b], 1);
      b = (unsigned)(v.z - lo); if (b < (unsigned)BPRO) atomicAdd(&h[b], 1);
      b = (unsigned)(v.w - lo); if (b < (unsigned)BPRO) atomicAdd(&h[b], 1);
    } else {
      for (int j = 0; j < 4; ++j) {
        const int ee = e + j;
        if (ee < E) {
          const unsigned b = (unsigned)(src[ee] - lo);
          if (b < (unsigned)BPRO) atomicAdd(&h[b], 1);
        }
      }
    }
  }
  __syncthreads();
  int* srow = slab + (size_t)cc * N;
  for (int i = tid; i < (BPRO >> 2); i += WG) {
    const int g = lo + (i << 2);
    if (g + 3 < N) {
      ((int4*)(srow + g))[0] = ((const int4*)h)[i];
    } else {
      for (int j = 0; j < 4; ++j)
        if (g + j < N) srow[g + j] = h[(i << 2) + j];
    }
  }
}

__global__ __launch_bounds__(WG) void dego_reduce_inv_kernel(const int* __restrict__ slab,
                                                             const int* __restrict__ degi,
                                                             float* __restrict__ invo,
                                                             float* __restrict__ invi, int N) {
  const int i = blockIdx.x * WG + threadIdx.x;
  if (i >= N) return;
  int s = 0;
#pragma unroll
  for (int c = 0; c < NCO; ++c) s += slab[(size_t)c * N + i];
  if (s < 1) s = 1;
  int dii = degi[i]; if (dii < 1) dii = 1;
  invo[i] = rsqrtf((float)s);
  invi[i] = rsqrtf((float)dii);
}

// --- weight transpose+convert: WT[c][k] = (f16)W[k][c] ----------------------
__global__ __launch_bounds__(WG) void wtrans_kernel(const float* __restrict__ W0,
                                                    const float* __restrict__ W1,
                                                    const float* __restrict__ W2,
                                                    const float* __restrict__ Wl,
                                                    _Float16* __restrict__ T0,
                                                    _Float16* __restrict__ T1,
                                                    _Float16* __restrict__ T2,
                                                    _Float16* __restrict__ Tl) {
  const float* W; _Float16* T; int K;
  switch (blockIdx.x) {
    case 0: W = W0; T = T0; K = 128; break;
    case 1: W = W1; T = T1; K = 64; break;
    case 2: W = W2; T = T2; K = 64; break;
    default: W = Wl; T = Tl; K = 64; break;
  }
  for (int i = threadIdx.x; i < K * 64; i += WG) {
    const int k = i >> 6, c = i & 63;
    T[c * K + k] = (_Float16)W[i];
  }
}

// --- MFMA conv GEMM: hP[r][c] = f16( invo[r] * sum_k in[r][k] W[k][c] ) -----
template <int K, bool F16IN>
__global__ __launch_bounds__(256) void gemm_conv_mfma(const void* __restrict__ inv_,
                                                      const _Float16* __restrict__ WT,
                                                      const float* __restrict__ invo,
                                                      _Float16* __restrict__ hP, int N) {
  const int tid = threadIdx.x;
  const int w = tid >> 6, l = tid & 63;
  const int rowA = blockIdx.x * 64 + w * 16 + (l & 15);
  const int ar = (rowA < N) ? rowA : (N - 1);
  const int g8 = (l >> 4) * 8;

  f32x4 acc[4];
#pragma unroll
  for (int t = 0; t < 4; ++t) acc[t] = (f32x4){0.f, 0.f, 0.f, 0.f};

#pragma unroll
  for (int s = 0; s < K / 32; ++s) {
    const int kb = s * 32 + g8;
    half8 a;
    if constexpr (F16IN) {
      a = *(const half8*)((const _Float16*)inv_ + (size_t)ar * K + kb);
    } else {
      const float* in = (const float*)inv_;
      const float4 f0 = *(const float4*)(in + (size_t)ar * K + kb);
      const float4 f1 = *(const float4*)(in + (size_t)ar * K + kb + 4);
      a[0] = (_Float16)f0.x; a[1] = (_Float16)f0.y; a[2] = (_Float16)f0.z; a[3] = (_Float16)f0.w;
      a[4] = (_Float16)f1.x; a[5] = (_Float16)f1.y; a[6] = (_Float16)f1.z; a[7] = (_Float16)f1.w;
    }
#pragma unroll
    for (int t = 0; t < 4; ++t) {
      const half8 b = *(const half8*)(WT + (size_t)(16 * t + (l & 15)) * K + kb);
      acc[t] = __builtin_amdgcn_mfma_f32_16x16x32_f16(a, b, acc[t], 0, 0, 0);
    }
  }

  const int rbase = blockIdx.x * 64 + w * 16 + (l >> 4) * 4;
#pragma unroll
  for (int r = 0; r < 4; ++r) {
    const int row = rbase + r;
    if (row < N) {
      const float sc = invo[row];
#pragma unroll
      for (int t = 0; t < 4; ++t)
        hP[(size_t)row * 64 + 16 * t + (l & 15)] = (_Float16)(acc[t][r] * sc);
    }
  }
}

// --- MFMA head GEMM (f16 in): out[r][c] = sum_k in[r][k] W[k][c] + bias[c] --
__global__ __launch_bounds__(256) void gemm_head_mfma(const _Float16* __restrict__ in,
                                                      const _Float16* __restrict__ WT,
                                                      const float* __restrict__ bias,
                                                      float* __restrict__ out, int N) {
  constexpr int K = 64;
  const int tid = threadIdx.x;
  const int w = tid >> 6, l = tid & 63;
  const int rowA = blockIdx.x * 64 + w * 16 + (l & 15);
  const int ar = (rowA < N) ? rowA : (N - 1);
  const int g8 = (l >> 4) * 8;

  f32x4 acc[4];
#pragma unroll
  for (int t = 0; t < 4; ++t) acc[t] = (f32x4){0.f, 0.f, 0.f, 0.f};

#pragma unroll
  for (int s = 0; s < K / 32; ++s) {
    const int kb = s * 32 + g8;
    const half8 a = *(const half8*)(in + (size_t)ar * K + kb);
#pragma unroll
    for (int t = 0; t < 4; ++t) {
      const half8 b = *(const half8*)(WT + (size_t)(16 * t + (l & 15)) * K + kb);
      acc[t] = __builtin_amdgcn_mfma_f32_16x16x32_f16(a, b, acc[t], 0, 0, 0);
    }
  }

  const int rbase = blockIdx.x * 64 + w * 16 + (l >> 4) * 4;
#pragma unroll
  for (int r = 0; r < 4; ++r) {
    const int row = rbase + r;
    if (row < N) {
#pragma unroll
      for (int t = 0; t < 4; ++t) {
        const int c = 16 * t + (l & 15);
        out[(size_t)row * 64 + c] = acc[t][r] + bias[c];
      }
    }
  }
}

// --- CSR gather aggregation, 8 lanes per row, distributed epilogue ----------
// lane = 8*g + f8; main loop: lane loads hp[esrc[e+g]*64 + f8*8..+8] (b128).
// Butterfly over g gives every lane all 8 sums of its f8 octet; lane then
// handles feature f8*8+g alone (7-cndmask mux), ELU via __expf, scalar store.
__global__ __launch_bounds__(256) void agg_kernel(const _Float16* __restrict__ hp,
                                                  const int* __restrict__ rptr,
                                                  const int* __restrict__ esrc,
                                                  const float* __restrict__ invin,
                                                  const float* __restrict__ bias,
                                                  _Float16* __restrict__ out, int N,
                                                  int apply_elu) {
  const int w = (blockIdx.x * 256 + threadIdx.x) >> 6;  // one wave per dst node
  const int lane = threadIdx.x & 63;
  const int g = lane >> 3;     // edge slot 0..7
  const int f8 = lane & 7;     // feature octet
  if (w >= N) return;
  const int e0 = rptr[w];
  const int e1 = rptr[w + 1];

  float acc[8];
#pragma unroll
  for (int k = 0; k < 8; ++k) acc[k] = 0.f;

  int e = e0;
  for (; e + 16 <= e1; e += 16) {   // 2 groups in flight
    const int sA = esrc[e + g];
    const int sB = esrc[e + 8 + g];
    const half8 hA8 = *(const half8*)(hp + (size_t)sA * 64 + f8 * 8);
    const half8 hB8 = *(const half8*)(hp + (size_t)sB * 64 + f8 * 8);
#pragma unroll
    for (int k = 0; k < 8; ++k) acc[k] += (float)hA8[k] + (float)hB8[k];
  }
  for (; e + 8 <= e1; e += 8) {
    const int s = esrc[e + g];
    const half8 hv = *(const half8*)(hp + (size_t)s * 64 + f8 * 8);
#pragma unroll
    for (int k = 0; k < 8; ++k) acc[k] += (float)hv[k];
  }
  if (e < e1) {                      // masked tail group
    const int rem = e1 - e;
    int idx = e + g; if (idx > e1 - 1) idx = e1 - 1;
    const int s = esrc[idx];
    const half8 hv = *(const half8*)(hp + (size_t)s * 64 + f8 * 8);
    const float m = (g < rem) ? 1.f : 0.f;
#pragma unroll
    for (int k = 0; k < 8; ++k) acc[k] = fmaf(m, (float)hv[k], acc[k]);
  }

  // butterfly reduce across the 8 edge slots (g); every lane gets all 8 sums
#pragma unroll
  for (int d = 8; d < 64; d <<= 1) {
#pragma unroll
    for (int k = 0; k < 8; ++k) acc[k] += __shfl_xor(acc[k], d);
  }

  // distributed epilogue: lane (g,f8) -> feature f8*8+g via static mux tree
  const bool b0 = (g & 1), b1 = (g & 2), b2 = (g & 4);
  const float s0 = b0 ? acc[1] : acc[0];
  const float s1 = b0 ? acc[3] : acc[2];
  const float s2 = b0 ? acc[5] : acc[4];
  const float s3 = b0 ? acc[7] : acc[6];
  const float t0 = b1 ? s1 : s0;
  const float t1 = b1 ? s3 : s2;
  float v = b2 ? t1 : t0;

  const int f = f8 * 8 + g;
  v = v * invin[w] + bias[f];
  if (apply_elu) v = (v > 0.f) ? v : (__expf(v) - 1.0f);
  out[(size_t)w * 64 + f] = (_Float16)v;
}

extern "C" void kernel_launch(void* const* d_in, const int* in_sizes, int n_in,
                              void* d_out, int out_size, void* d_ws, size_t ws_size,
                              hipStream_t stream) {
  const float* x  = (const float*)d_in[0];
  const int*   src = (const int*)d_in[1];
  const int*   dst = (const int*)d_in[2];
  const float* W0 = (const float*)d_in[3];
  const float* b0 = (const float*)d_in[4];
  const float* W1 = (const float*)d_in[5];
  const float* b1 = (const float*)d_in[6];
  const float* W2 = (const float*)d_in[7];
  const float* b2 = (const float*)d_in[8];
  const float* Wl = (const float*)d_in[9];
  const float* bl = (const float*)d_in[10];

  const int N = in_sizes[0] / 128;
  const int E = in_sizes[1];
  const int NR = (N + RWID - 1) >> RW_SH;
  const int EPC = (((E + NCHUNK - 1) / NCHUNK) + 3) & ~3;
  const int EPCO = (((E + NCO - 1) / NCO) + 3) & ~3;

  int* wsp = (int*)d_ws;
  size_t off = 0;
  auto alloc = [&](size_t n) -> int* {   // 256B-aligned regions
    int* p = wsp + off;
    off += (n + 63) & ~(size_t)63;
    return p;
  };
  int*      degi       = alloc(N);
  float*    invo       = (float*)alloc(N);
  float*    invi       = (float*)alloc(N);
  int*      rptr       = alloc((size_t)N + 1);
  int*      esrc       = alloc(E);
  int*      cntA       = alloc((size_t)NR * NCHUNK);
  int*      base_rel   = alloc((size_t)NR * NCHUNK);
  int*      cntR       = alloc(NR);
  int*      rangeStart = alloc((size_t)NR + 1);
  int*      bucket     = alloc(E);
  int*      slab       = alloc((size_t)NCO * N);
  _Float16* hP         = (_Float16*)alloc((size_t)N * 32);  // N x 64 f16
  _Float16* hA         = (_Float16*)alloc((size_t)N * 32);  // N x 64 f16
  _Float16* WT0        = (_Float16*)alloc(64 * 128 / 2);
  _Float16* WT1        = (_Float16*)alloc(64 * 64 / 2);
  _Float16* WT2        = (_Float16*)alloc(64 * 64 / 2);
  _Float16* WTl        = (_Float16*)alloc(64 * 64 / 2);
  (void)ws_size; (void)n_in; (void)out_size;

  const int gN = (N + WG - 1) / WG;
  const int gAgg = (N + 3) / 4;
  const int gGemm = (N + 63) / 64;

  // CSR-by-dst build (atomic-free at global scope)
  coarse_hist_kernel<<<NCHUNK, WG, 0, stream>>>(dst, cntA, NR, E, EPC);
  chunkscan_kernel<<<NR, WG, 0, stream>>>(cntA, base_rel, cntR);
  rangescan_kernel<<<1, WG, 0, stream>>>(cntR, rangeStart, rptr, NR, N, E);
  bucket_kernel<<<NCHUNK, WG, 0, stream>>>(src, dst, base_rel, rangeStart, bucket, NR, E, EPC);
  csr_kernel<<<NR, WG, 0, stream>>>(bucket, rangeStart, rptr, degi, esrc, N);

  // out-degree via privatized LDS histograms + fused inv; weight transposes
  dego_hist_kernel<<<NRO * NCO, WG, 0, stream>>>(src, slab, N, E, EPCO);
  dego_reduce_inv_kernel<<<gN, WG, 0, stream>>>(slab, degi, invo, invi, N);
  wtrans_kernel<<<4, WG, 0, stream>>>(W0, W1, W2, Wl, WT0, WT1, WT2, WTl);

  // layer 0: (x@W0)*invo -> agg -> *invi+b0 -> elu
  gemm_conv_mfma<128, false><<<gGemm, 256, 0, stream>>>(x, WT0, invo, hP, N);
  agg_kernel<<<gAgg, 256, 0, stream>>>(hP, rptr, esrc, invi, b0, hA, N, 1);
  // layer 1
  gemm_conv_mfma<64, true><<<gGemm, 256, 0, stream>>>(hA, WT1, invo, hP, N);
  agg_kernel<<<gAgg, 256, 0, stream>>>(hP, rptr, esrc, invi, b1, hA, N, 1);
  // layer 2 (+ fused elu ahead of the linear head)
  gemm_conv_mfma<64, true><<<gGemm, 256, 0, stream>>>(hA, WT2, invo, hP, N);
  agg_kernel<<<gAgg, 256, 0, stream>>>(hP, rptr, esrc, invi, b2, hA, N, 1);
  // head: elu(h2) @ Wl + bl
  gemm_head_mfma<<<gGemm, 256, 0, stream>>>(hA, WTl, bl, (float*)d_out, N);
}

// Round 8
// 266.722 us; speedup vs baseline: 2.1181x; 1.0174x over previous
//
#include <hip/hip_runtime.h>
#include <hip/hip_fp16.h>
#include <cstdint>
#include <cstddef>

// ---------------------------------------------------------------------------
// GCN: 3x GraphConv(norm='both') + linear head, fp32 in/out.
// Round 8 (agg only):
//  - accumulate via v_dot2_f32_f16 (pack 2 edges' same feature -> 1 fdot2)
//  - reduce-scatter butterfly (mux-as-you-go): 14 cndmask + 7 shfl + 7 add
//    replaces full 24-shfl butterfly + 7-mux epilogue
//  - invin/bias hoisted above the gather loop
//  - rest unchanged: MFMA GEMMs, atomic-free CSR, dego LDS histogram
// ---------------------------------------------------------------------------

#define WG 256
static constexpr int NCHUNK = 512;   // edge chunks for dst bucketing
static constexpr int RW_SH  = 7;     // range width = 128 nodes (dst>>7)
static constexpr int RWID   = 1 << RW_SH;
static constexpr int BPRO   = 6256;  // bins per range for dego histogram (25KB)
static constexpr int NRO    = 16;    // dego ranges (16*6256 >= 100000)
static constexpr int NCO    = 40;    // edge chunks for dego histogram

typedef _Float16 half8 __attribute__((ext_vector_type(8)));
typedef _Float16 half2v __attribute__((ext_vector_type(2)));
typedef float f32x4 __attribute__((ext_vector_type(4)));

__device__ __forceinline__ int block_scan_excl(int v, int tid, int* sd, int& total) {
  sd[tid] = v;
  __syncthreads();
  for (int off = 1; off < 256; off <<= 1) {
    int t = (tid >= off) ? sd[tid - off] : 0;
    __syncthreads();
    sd[tid] += t;
    __syncthreads();
  }
  int incl = sd[tid];
  total = sd[255];
  __syncthreads();
  return incl - v;
}

// --- Pass A: per-chunk coarse histogram over dst ranges ---------------------
__global__ __launch_bounds__(WG) void coarse_hist_kernel(const int* __restrict__ dst,
                                                         int* __restrict__ cntA,
                                                         int NR, int E, int EPC) {
  __shared__ int cnt[1024];
  const int c = blockIdx.x, tid = threadIdx.x;
  for (int i = tid; i < NR; i += WG) cnt[i] = 0;
  __syncthreads();
  const int base = c * EPC;
  const int nv4 = EPC >> 2;
  const int4* d4 = (const int4*)(dst + base);
  for (int i = tid; i < nv4; i += WG) {
    const int e = base + (i << 2);
    if (e + 3 < E) {
      const int4 v = d4[i];
      atomicAdd(&cnt[v.x >> RW_SH], 1);
      atomicAdd(&cnt[v.y >> RW_SH], 1);
      atomicAdd(&cnt[v.z >> RW_SH], 1);
      atomicAdd(&cnt[v.w >> RW_SH], 1);
    } else {
      for (int j = 0; j < 4; ++j) {
        const int ee = e + j;
        if (ee < E) atomicAdd(&cnt[dst[ee] >> RW_SH], 1);
      }
    }
  }
  __syncthreads();
  for (int i = tid; i < NR; i += WG) cntA[i * NCHUNK + c] = cnt[i];
}

// --- Pass B1: per-range exclusive scan over the 512 chunks ------------------
__global__ __launch_bounds__(WG) void chunkscan_kernel(const int* __restrict__ cntA,
                                                       int* __restrict__ base_rel,
                                                       int* __restrict__ cntR) {
  __shared__ int sd[256];
  const int r = blockIdx.x, tid = threadIdx.x;
  const int row = r * NCHUNK;
  int t0, t1;
  const int v0 = cntA[row + tid];
  const int e0 = block_scan_excl(v0, tid, sd, t0);
  base_rel[row + tid] = e0;
  const int v1 = cntA[row + 256 + tid];
  const int e1 = block_scan_excl(v1, tid, sd, t1);
  base_rel[row + 256 + tid] = t0 + e1;
  if (tid == 0) cntR[r] = t0 + t1;
}

// --- Pass B2: exclusive scan over up to 1024 ranges -> rangeStart -----------
__global__ __launch_bounds__(WG) void rangescan_kernel(const int* __restrict__ cntR,
                                                       int* __restrict__ rangeStart,
                                                       int* __restrict__ rptr,
                                                       int NR, int N, int E) {
  __shared__ int sd[256];
  const int tid = threadIdx.x;
  int carry = 0;
  for (int base = 0; base < NR; base += 256) {
    const int idx = base + tid;
    const int v = (idx < NR) ? cntR[idx] : 0;
    int tot;
    const int e = block_scan_excl(v, tid, sd, tot);
    if (idx < NR) rangeStart[idx] = carry + e;
    carry += tot;
  }
  if (tid == 0) { rangeStart[NR] = E; rptr[N] = E; }
}

// --- Pass C: bucket scatter with LDS cursors, 4B packed entries -------------
__global__ __launch_bounds__(WG) void bucket_kernel(const int* __restrict__ src,
                                                    const int* __restrict__ dst,
                                                    const int* __restrict__ base_rel,
                                                    const int* __restrict__ rangeStart,
                                                    int* __restrict__ bucket,
                                                    int NR, int E, int EPC) {
  __shared__ int cur[1024];
  const int c = blockIdx.x, tid = threadIdx.x;
  for (int i = tid; i < NR; i += WG) cur[i] = rangeStart[i] + base_rel[i * NCHUNK + c];
  __syncthreads();
  const int base = c * EPC;
  const int nv4 = EPC >> 2;
  const int4* s4 = (const int4*)(src + base);
  const int4* d4 = (const int4*)(dst + base);
  for (int i = tid; i < nv4; i += WG) {
    const int e = base + (i << 2);
    if (e + 3 < E) {
      const int4 sv = s4[i];
      const int4 dv = d4[i];
      int p;
      p = atomicAdd(&cur[dv.x >> RW_SH], 1); bucket[p] = (sv.x << RW_SH) | (dv.x & (RWID - 1));
      p = atomicAdd(&cur[dv.y >> RW_SH], 1); bucket[p] = (sv.y << RW_SH) | (dv.y & (RWID - 1));
      p = atomicAdd(&cur[dv.z >> RW_SH], 1); bucket[p] = (sv.z << RW_SH) | (dv.z & (RWID - 1));
      p = atomicAdd(&cur[dv.w >> RW_SH], 1); bucket[p] = (sv.w << RW_SH) | (dv.w & (RWID - 1));
    } else {
      for (int j = 0; j < 4; ++j) {
        const int ee = e + j;
        if (ee < E) {
          const int s = src[ee], d = dst[ee];
          const int p = atomicAdd(&cur[d >> RW_SH], 1);
          bucket[p] = (s << RW_SH) | (d & (RWID - 1));
        }
      }
    }
  }
}

// --- Pass D: per-range CSR finalize (rptr, degi, esrc) ----------------------
__global__ __launch_bounds__(WG) void csr_kernel(const int* __restrict__ bucket,
                                                 const int* __restrict__ rangeStart,
                                                 int* __restrict__ rptr,
                                                 int* __restrict__ degi,
                                                 int* __restrict__ esrc, int N) {
  __shared__ int hist[RWID], sd[256];
  const int r = blockIdx.x, tid = threadIdx.x;
  const int s0 = rangeStart[r], s1 = rangeStart[r + 1];
  if (tid < RWID) hist[tid] = 0;
  __syncthreads();
  for (int e = s0 + tid; e < s1; e += WG) atomicAdd(&hist[bucket[e] & (RWID - 1)], 1);
  __syncthreads();
  const int v = (tid < RWID) ? hist[tid] : 0;
  int tot;
  const int excl = block_scan_excl(v, tid, sd, tot);
  const int node = (r << RW_SH) + tid;
  if (tid < RWID && node < N) { degi[node] = v; rptr[node] = s0 + excl; }
  if (tid < RWID) hist[tid] = s0 + excl;
  __syncthreads();
  for (int e = s0 + tid; e < s1; e += WG) {
    const int pk = bucket[e];
    const int p = atomicAdd(&hist[pk & (RWID - 1)], 1);
    esrc[p] = pk >> RW_SH;
  }
}

// --- dego: privatized LDS histogram over src, slab + reduce + inv -----------
__global__ __launch_bounds__(WG) void dego_hist_kernel(const int* __restrict__ src,
                                                       int* __restrict__ slab,
                                                       int N, int E, int EPCO) {
  __shared__ int h[BPRO];  // 25 KB
  const int rr = blockIdx.x / NCO, cc = blockIdx.x % NCO;
  const int tid = threadIdx.x;
  for (int i = tid; i < (BPRO >> 2); i += WG) ((int4*)h)[i] = make_int4(0, 0, 0, 0);
  __syncthreads();
  const int lo = rr * BPRO;
  const int base = cc * EPCO;
  const int nv4 = EPCO >> 2;
  const int4* s4 = (const int4*)(src + base);
  for (int i = tid; i < nv4; i += WG) {
    const int e = base + (i << 2);
    if (e + 3 < E) {
      const int4 v = s4[i];
      unsigned b;
      b = (unsigned)(v.x - lo); if (b < (unsigned)BPRO) atomicAdd(&h[b], 1);
      b = (unsigned)(v.y - lo); if (b < (unsigned)BPRO) atomicAdd(&h[b], 1);
      b = (unsigned)(v.z - lo); if (b < (unsigned)BPRO) atomicAdd(&h[b], 1);
      b = (unsigned)(v.w - lo); if (b < (unsigned)BPRO) atomicAdd(&h[b], 1);
    } else {
      for (int j = 0; j < 4; ++j) {
        const int ee = e + j;
        if (ee < E) {
          const unsigned b = (unsigned)(src[ee] - lo);
          if (b < (unsigned)BPRO) atomicAdd(&h[b], 1);
        }
      }
    }
  }
  __syncthreads();
  int* srow = slab + (size_t)cc * N;
  for (int i = tid; i < (BPRO >> 2); i += WG) {
    const int g = lo + (i << 2);
    if (g + 3 < N) {
      ((int4*)(srow + g))[0] = ((const int4*)h)[i];
    } else {
      for (int j = 0; j < 4; ++j)
        if (g + j < N) srow[g + j] = h[(i << 2) + j];
    }
  }
}

__global__ __launch_bounds__(WG) void dego_reduce_inv_kernel(const int* __restrict__ slab,
                                                             const int* __restrict__ degi,
                                                             float* __restrict__ invo,
                                                             float* __restrict__ invi, int N) {
  const int i = blockIdx.x * WG + threadIdx.x;
  if (i >= N) return;
  int s = 0;
#pragma unroll
  for (int c = 0; c < NCO; ++c) s += slab[(size_t)c * N + i];
  if (s < 1) s = 1;
  int dii = degi[i]; if (dii < 1) dii = 1;
  invo[i] = rsqrtf((float)s);
  invi[i] = rsqrtf((float)dii);
}

// --- weight transpose+convert: WT[c][k] = (f16)W[k][c] ----------------------
__global__ __launch_bounds__(WG) void wtrans_kernel(const float* __restrict__ W0,
                                                    const float* __restrict__ W1,
                                                    const float* __restrict__ W2,
                                                    const float* __restrict__ Wl,
                                                    _Float16* __restrict__ T0,
                                                    _Float16* __restrict__ T1,
                                                    _Float16* __restrict__ T2,
                                                    _Float16* __restrict__ Tl) {
  const float* W; _Float16* T; int K;
  switch (blockIdx.x) {
    case 0: W = W0; T = T0; K = 128; break;
    case 1: W = W1; T = T1; K = 64; break;
    case 2: W = W2; T = T2; K = 64; break;
    default: W = Wl; T = Tl; K = 64; break;
  }
  for (int i = threadIdx.x; i < K * 64; i += WG) {
    const int k = i >> 6, c = i & 63;
    T[c * K + k] = (_Float16)W[i];
  }
}

// --- MFMA conv GEMM: hP[r][c] = f16( invo[r] * sum_k in[r][k] W[k][c] ) -----
template <int K, bool F16IN>
__global__ __launch_bounds__(256) void gemm_conv_mfma(const void* __restrict__ inv_,
                                                      const _Float16* __restrict__ WT,
                                                      const float* __restrict__ invo,
                                                      _Float16* __restrict__ hP, int N) {
  const int tid = threadIdx.x;
  const int w = tid >> 6, l = tid & 63;
  const int rowA = blockIdx.x * 64 + w * 16 + (l & 15);
  const int ar = (rowA < N) ? rowA : (N - 1);
  const int g8 = (l >> 4) * 8;

  f32x4 acc[4];
#pragma unroll
  for (int t = 0; t < 4; ++t) acc[t] = (f32x4){0.f, 0.f, 0.f, 0.f};

#pragma unroll
  for (int s = 0; s < K / 32; ++s) {
    const int kb = s * 32 + g8;
    half8 a;
    if constexpr (F16IN) {
      a = *(const half8*)((const _Float16*)inv_ + (size_t)ar * K + kb);
    } else {
      const float* in = (const float*)inv_;
      const float4 f0 = *(const float4*)(in + (size_t)ar * K + kb);
      const float4 f1 = *(const float4*)(in + (size_t)ar * K + kb + 4);
      a[0] = (_Float16)f0.x; a[1] = (_Float16)f0.y; a[2] = (_Float16)f0.z; a[3] = (_Float16)f0.w;
      a[4] = (_Float16)f1.x; a[5] = (_Float16)f1.y; a[6] = (_Float16)f1.z; a[7] = (_Float16)f1.w;
    }
#pragma unroll
    for (int t = 0; t < 4; ++t) {
      const half8 b = *(const half8*)(WT + (size_t)(16 * t + (l & 15)) * K + kb);
      acc[t] = __builtin_amdgcn_mfma_f32_16x16x32_f16(a, b, acc[t], 0, 0, 0);
    }
  }

  const int rbase = blockIdx.x * 64 + w * 16 + (l >> 4) * 4;
#pragma unroll
  for (int r = 0; r < 4; ++r) {
    const int row = rbase + r;
    if (row < N) {
      const float sc = invo[row];
#pragma unroll
      for (int t = 0; t < 4; ++t)
        hP[(size_t)row * 64 + 16 * t + (l & 15)] = (_Float16)(acc[t][r] * sc);
    }
  }
}

// --- MFMA head GEMM (f16 in): out[r][c] = sum_k in[r][k] W[k][c] + bias[c] --
__global__ __launch_bounds__(256) void gemm_head_mfma(const _Float16* __restrict__ in,
                                                      const _Float16* __restrict__ WT,
                                                      const float* __restrict__ bias,
                                                      float* __restrict__ out, int N) {
  constexpr int K = 64;
  const int tid = threadIdx.x;
  const int w = tid >> 6, l = tid & 63;
  const int rowA = blockIdx.x * 64 + w * 16 + (l & 15);
  const int ar = (rowA < N) ? rowA : (N - 1);
  const int g8 = (l >> 4) * 8;

  f32x4 acc[4];
#pragma unroll
  for (int t = 0; t < 4; ++t) acc[t] = (f32x4){0.f, 0.f, 0.f, 0.f};

#pragma unroll
  for (int s = 0; s < K / 32; ++s) {
    const int kb = s * 32 + g8;
    const half8 a = *(const half8*)(in + (size_t)ar * K + kb);
#pragma unroll
    for (int t = 0; t < 4; ++t) {
      const half8 b = *(const half8*)(WT + (size_t)(16 * t + (l & 15)) * K + kb);
      acc[t] = __builtin_amdgcn_mfma_f32_16x16x32_f16(a, b, acc[t], 0, 0, 0);
    }
  }

  const int rbase = blockIdx.x * 64 + w * 16 + (l >> 4) * 4;
#pragma unroll
  for (int r = 0; r < 4; ++r) {
    const int row = rbase + r;
    if (row < N) {
#pragma unroll
      for (int t = 0; t < 4; ++t) {
        const int c = 16 * t + (l & 15);
        out[(size_t)row * 64 + c] = acc[t][r] + bias[c];
      }
    }
  }
}

// --- CSR gather aggregation, 8 lanes per row --------------------------------
// lane = 8*g + f8; gather: hp[esrc[e+g]*64 + f8*8..+8] (b128, 8 edges/wave-ld)
// accumulate: fdot2 packs 2 edges' same feature. reduce-scatter butterfly
// (mux-as-you-go) leaves lane (g,f8) holding feature f8*8+g.
__global__ __launch_bounds__(256) void agg_kernel(const _Float16* __restrict__ hp,
                                                  const int* __restrict__ rptr,
                                                  const int* __restrict__ esrc,
                                                  const float* __restrict__ invin,
                                                  const float* __restrict__ bias,
                                                  _Float16* __restrict__ out, int N,
                                                  int apply_elu) {
  const int w = (blockIdx.x * 256 + threadIdx.x) >> 6;  // one wave per dst node
  const int lane = threadIdx.x & 63;
  const int g = lane >> 3;     // edge slot 0..7
  const int f8 = lane & 7;     // feature octet
  if (w >= N) return;
  const int e0 = rptr[w];
  const int e1 = rptr[w + 1];
  const int f = f8 * 8 + g;
  const float vi = invin[w];        // hoisted: not on the epilogue dep chain
  const float bv = bias[f];

  float acc[8];
#pragma unroll
  for (int k = 0; k < 8; ++k) acc[k] = 0.f;

  int e = e0;
  for (; e + 16 <= e1; e += 16) {   // 2 groups in flight, fdot2 accumulate
    const int sA = esrc[e + g];
    const int sB = esrc[e + 8 + g];
    const half8 hA8 = *(const half8*)(hp + (size_t)sA * 64 + f8 * 8);
    const half8 hB8 = *(const half8*)(hp + (size_t)sB * 64 + f8 * 8);
#if __has_builtin(__builtin_amdgcn_fdot2)
    const half2v one2 = {(_Float16)1.0f, (_Float16)1.0f};
#pragma unroll
    for (int k = 0; k < 8; ++k) {
      half2v p; p[0] = hA8[k]; p[1] = hB8[k];
      acc[k] = __builtin_amdgcn_fdot2(p, one2, acc[k], false);
    }
#else
#pragma unroll
    for (int k = 0; k < 8; ++k) acc[k] += (float)hA8[k] + (float)hB8[k];
#endif
  }
  for (; e + 8 <= e1; e += 8) {
    const int s = esrc[e + g];
    const half8 hv = *(const half8*)(hp + (size_t)s * 64 + f8 * 8);
#pragma unroll
    for (int k = 0; k < 8; ++k) acc[k] += (float)hv[k];
  }
  if (e < e1) {                      // masked tail group
    const int rem = e1 - e;
    int idx = e + g; if (idx > e1 - 1) idx = e1 - 1;
    const int s = esrc[idx];
    const half8 hv = *(const half8*)(hp + (size_t)s * 64 + f8 * 8);
    const float m = (g < rem) ? 1.f : 0.f;
#pragma unroll
    for (int k = 0; k < 8; ++k) acc[k] = fmaf(m, (float)hv[k], acc[k]);
  }

  // reduce-scatter butterfly: each round sends the half the partner keeps.
  // Round 1 (xor 8, g bit0): 8 accs -> 4
  const bool gb0 = (g & 1) != 0;
  const float s0 = gb0 ? acc[0] : acc[1];
  const float s1 = gb0 ? acc[2] : acc[3];
  const float s2 = gb0 ? acc[4] : acc[5];
  const float s3 = gb0 ? acc[6] : acc[7];
  const float k0 = (gb0 ? acc[1] : acc[0]) + __shfl_xor(s0, 8);
  const float k1 = (gb0 ? acc[3] : acc[2]) + __shfl_xor(s1, 8);
  const float k2 = (gb0 ? acc[5] : acc[4]) + __shfl_xor(s2, 8);
  const float k3 = (gb0 ? acc[7] : acc[6]) + __shfl_xor(s3, 8);
  // Round 2 (xor 16, g bit1): 4 -> 2
  const bool gb1 = (g & 2) != 0;
  const float t0 = gb1 ? k0 : k1;
  const float t1 = gb1 ? k2 : k3;
  const float m0 = (gb1 ? k1 : k0) + __shfl_xor(t0, 16);
  const float m1 = (gb1 ? k3 : k2) + __shfl_xor(t1, 16);
  // Round 3 (xor 32, g bit2): 2 -> 1 (lane holds feature f = f8*8+g)
  const bool gb2 = (g & 4) != 0;
  const float u0 = gb2 ? m0 : m1;
  float v = (gb2 ? m1 : m0) + __shfl_xor(u0, 32);

  v = v * vi + bv;
  if (apply_elu) v = (v > 0.f) ? v : (__expf(v) - 1.0f);
  out[(size_t)w * 64 + f] = (_Float16)v;
}

extern "C" void kernel_launch(void* const* d_in, const int* in_sizes, int n_in,
                              void* d_out, int out_size, void* d_ws, size_t ws_size,
                              hipStream_t stream) {
  const float* x  = (const float*)d_in[0];
  const int*   src = (const int*)d_in[1];
  const int*   dst = (const int*)d_in[2];
  const float* W0 = (const float*)d_in[3];
  const float* b0 = (const float*)d_in[4];
  const float* W1 = (const float*)d_in[5];
  const float* b1 = (const float*)d_in[6];
  const float* W2 = (const float*)d_in[7];
  const float* b2 = (const float*)d_in[8];
  const float* Wl = (const float*)d_in[9];
  const float* bl = (const float*)d_in[10];

  const int N = in_sizes[0] / 128;
  const int E = in_sizes[1];
  const int NR = (N + RWID - 1) >> RW_SH;
  const int EPC = (((E + NCHUNK - 1) / NCHUNK) + 3) & ~3;
  const int EPCO = (((E + NCO - 1) / NCO) + 3) & ~3;

  int* wsp = (int*)d_ws;
  size_t off = 0;
  auto alloc = [&](size_t n) -> int* {   // 256B-aligned regions
    int* p = wsp + off;
    off += (n + 63) & ~(size_t)63;
    return p;
  };
  int*      degi       = alloc(N);
  float*    invo       = (float*)alloc(N);
  float*    invi       = (float*)alloc(N);
  int*      rptr       = alloc((size_t)N + 1);
  int*      esrc       = alloc(E);
  int*      cntA       = alloc((size_t)NR * NCHUNK);
  int*      base_rel   = alloc((size_t)NR * NCHUNK);
  int*      cntR       = alloc(NR);
  int*      rangeStart = alloc((size_t)NR + 1);
  int*      bucket     = alloc(E);
  int*      slab       = alloc((size_t)NCO * N);
  _Float16* hP         = (_Float16*)alloc((size_t)N * 32);  // N x 64 f16
  _Float16* hA         = (_Float16*)alloc((size_t)N * 32);  // N x 64 f16
  _Float16* WT0        = (_Float16*)alloc(64 * 128 / 2);
  _Float16* WT1        = (_Float16*)alloc(64 * 64 / 2);
  _Float16* WT2        = (_Float16*)alloc(64 * 64 / 2);
  _Float16* WTl        = (_Float16*)alloc(64 * 64 / 2);
  (void)ws_size; (void)n_in; (void)out_size;

  const int gN = (N + WG - 1) / WG;
  const int gAgg = (N + 3) / 4;
  const int gGemm = (N + 63) / 64;

  // CSR-by-dst build (atomic-free at global scope)
  coarse_hist_kernel<<<NCHUNK, WG, 0, stream>>>(dst, cntA, NR, E, EPC);
  chunkscan_kernel<<<NR, WG, 0, stream>>>(cntA, base_rel, cntR);
  rangescan_kernel<<<1, WG, 0, stream>>>(cntR, rangeStart, rptr, NR, N, E);
  bucket_kernel<<<NCHUNK, WG, 0, stream>>>(src, dst, base_rel, rangeStart, bucket, NR, E, EPC);
  csr_kernel<<<NR, WG, 0, stream>>>(bucket, rangeStart, rptr, degi, esrc, N);

  // out-degree via privatized LDS histograms + fused inv; weight transposes
  dego_hist_kernel<<<NRO * NCO, WG, 0, stream>>>(src, slab, N, E, EPCO);
  dego_reduce_inv_kernel<<<gN, WG, 0, stream>>>(slab, degi, invo, invi, N);
  wtrans_kernel<<<4, WG, 0, stream>>>(W0, W1, W2, Wl, WT0, WT1, WT2, WTl);

  // layer 0: (x@W0)*invo -> agg -> *invi+b0 -> elu
  gemm_conv_mfma<128, false><<<gGemm, 256, 0, stream>>>(x, WT0, invo, hP, N);
  agg_kernel<<<gAgg, 256, 0, stream>>>(hP, rptr, esrc, invi, b0, hA, N, 1);
  // layer 1
  gemm_conv_mfma<64, true><<<gGemm, 256, 0, stream>>>(hA, WT1, invo, hP, N);
  agg_kernel<<<gAgg, 256, 0, stream>>>(hP, rptr, esrc, invi, b1, hA, N, 1);
  // layer 2 (+ fused elu ahead of the linear head)
  gemm_conv_mfma<64, true><<<gGemm, 256, 0, stream>>>(hA, WT2, invo, hP, N);
  agg_kernel<<<gAgg, 256, 0, stream>>>(hP, rptr, esrc, invi, b2, hA, N, 1);
  // head: elu(h2) @ Wl + bl
  gemm_head_mfma<<<gGemm, 256, 0, stream>>>(hA, WTl, bl, (float*)d_out, N);
}